// Round 1
// baseline (1048.405 us; speedup 1.0000x reference)
//
#include <hip/hip_runtime.h>
#include <cmath>

typedef __attribute__((ext_vector_type(8))) short bf16x8;
typedef __attribute__((ext_vector_type(4))) float f32x4;
typedef unsigned short u16;

__device__ __forceinline__ u16 f2bf(float f) {
  union { float f; unsigned u; } x; x.f = f;
  return (u16)((x.u + 0x7FFFu + ((x.u >> 16) & 1u)) >> 16);
}

__device__ __forceinline__ void gload_lds16(const void* g, void* l) {
  __builtin_amdgcn_global_load_lds((const __attribute__((address_space(1))) unsigned*)g,
                                   (__attribute__((address_space(3))) unsigned*)l,
                                   16, 0, 0);
}

__global__ __launch_bounds__(256) void cast_bf16_kernel(const float* __restrict__ in,
                                                        u16* __restrict__ out, long n) {
  long i = (long)blockIdx.x * blockDim.x + threadIdx.x;
  long stride = (long)gridDim.x * blockDim.x;
  for (long j = i * 4; j < n; j += stride * 4) {
    float4 v = *(const float4*)(in + j);
    ushort4 o;
    o.x = f2bf(v.x); o.y = f2bf(v.y); o.z = f2bf(v.z); o.w = f2bf(v.w);
    *(ushort4*)(out + j) = o;
  }
}

// C = A[M,K] * B[N,K]^T, bf16 inputs, f32 accumulate.
// EPI 0: RoPE + scale, write bf16 to (b, h, t, d) layout (tile col range == one head)
// EPI 1: plain bf16 write to (b, h, t, d)
// EPI 2: plain f32 write to [M, N]
template <int EPI>
__global__ __launch_bounds__(256) void gemm_bt(const u16* __restrict__ A,
                                               const u16* __restrict__ B,
                                               void* __restrict__ outp,
                                               int M, int N, int K,
                                               const float* __restrict__ cosp,
                                               const float* __restrict__ sinp,
                                               float scale) {
  __shared__ u16 As[128 * 64];
  __shared__ u16 Bs[128 * 64];
  const int tid = threadIdx.x;
  const int lane = tid & 63;
  const int l16 = lane & 15, lhi = lane >> 4;
  const int w = tid >> 6;
  const int wr = w >> 1, wc = w & 1;
  const int m0 = blockIdx.y * 128;
  const int n0 = blockIdx.x * 128;
  const int wbase = tid - lane;

  f32x4 acc[4][4];
#pragma unroll
  for (int i = 0; i < 4; ++i)
#pragma unroll
    for (int j = 0; j < 4; ++j) acc[i][j] = (f32x4)0.0f;

  for (int k0 = 0; k0 < K; k0 += 64) {
    __syncthreads();
#pragma unroll
    for (int j = 0; j < 4; ++j) {
      int c = tid + j * 256;
      gload_lds16(A + (size_t)(m0 + (c >> 3)) * K + k0 + (c & 7) * 8,
                  As + (size_t)(wbase + j * 256) * 8);
    }
#pragma unroll
    for (int j = 0; j < 4; ++j) {
      int c = tid + j * 256;
      gload_lds16(B + (size_t)(n0 + (c >> 3)) * K + k0 + (c & 7) * 8,
                  Bs + (size_t)(wbase + j * 256) * 8);
    }
    __syncthreads();
#pragma unroll
    for (int kk = 0; kk < 64; kk += 32) {
      bf16x8 af[4], bfr[4];
#pragma unroll
      for (int mi = 0; mi < 4; ++mi)
        af[mi] = *(const bf16x8*)&As[(wr * 64 + mi * 16 + l16) * 64 + kk + lhi * 8];
#pragma unroll
      for (int ni = 0; ni < 4; ++ni)
        bfr[ni] = *(const bf16x8*)&Bs[(wc * 64 + ni * 16 + l16) * 64 + kk + lhi * 8];
#pragma unroll
      for (int mi = 0; mi < 4; ++mi)
#pragma unroll
        for (int ni = 0; ni < 4; ++ni)
          acc[mi][ni] = __builtin_amdgcn_mfma_f32_16x16x32_bf16(af[mi], bfr[ni], acc[mi][ni], 0, 0, 0);
    }
  }

  if (EPI == 2) {
    float* o = (float*)outp;
#pragma unroll
    for (int mi = 0; mi < 4; ++mi)
#pragma unroll
      for (int r = 0; r < 4; ++r) {
        int row = m0 + wr * 64 + mi * 16 + lhi * 4 + r;
#pragma unroll
        for (int ni = 0; ni < 4; ++ni) {
          int col = n0 + wc * 64 + ni * 16 + l16;
          o[(size_t)row * N + col] = acc[mi][ni][r];
        }
      }
  } else {
    u16* o = (u16*)outp;
    const int nheads = N >> 7;
    const int h = blockIdx.x;
#pragma unroll
    for (int mi = 0; mi < 4; ++mi)
#pragma unroll
      for (int r = 0; r < 4; ++r) {
        int row = m0 + wr * 64 + mi * 16 + lhi * 4 + r;
        int b = row >> 11;
        int t = row & 2047;
        size_t base = ((size_t)(b * nheads + h) * 2048 + t) * 128;
#pragma unroll
        for (int ni = 0; ni < 4; ++ni) {
          int d = wc * 64 + ni * 16 + l16;
          float v = acc[mi][ni][r];
          if (EPI == 0) {
            float p = __shfl_xor(v, 1);
            float c = cosp[t * 64 + (d >> 1)];
            float s = sinp[t * 64 + (d >> 1)];
            v = (lane & 1) ? fmaf(p, s, v * c) : fmaf(v, c, -p * s);
            v *= scale;
          }
          o[base + d] = f2bf(v);
        }
      }
  }
}

// Flash attention: Q (B,H,T,D) bf16, K/V (B,HKV,T,D) bf16 -> O (B,T,H*D) bf16.
// Block = (b, h, 64-row q tile); 4 waves x 16 q-rows. 1/sqrt(D)*log2(e) pre-folded into Q.
__global__ __launch_bounds__(256) void attn_kernel(const u16* __restrict__ Q,
                                                   const u16* __restrict__ Kp,
                                                   const u16* __restrict__ Vp,
                                                   u16* __restrict__ O) {
  __shared__ u16 Ks[64 * 128];
  __shared__ u16 VT[128 * 72];   // V transposed [d][kv], +8 pad
  __shared__ u16 PO[4][2048];    // per-wave: P [16][72] during loop, O [16][128] at end

  const int tid = threadIdx.x;
  const int lane = tid & 63;
  const int w = tid >> 6;
  const int l16 = lane & 15, lhi = lane >> 4;
  const int bid = blockIdx.x;
  const int qt = bid & 31;
  const int h = (bid >> 5) & 15;
  const int b = bid >> 9;
  const int kvh = h >> 2;
  const int q0 = qt * 64;
  const int wbase = tid - lane;

  const u16* Qb = Q + ((size_t)((b * 16 + h) * 2048 + q0 + w * 16)) * 128;
  const u16* Kb = Kp + (size_t)(b * 4 + kvh) * 2048 * 128;
  const u16* Vb = Vp + (size_t)(b * 4 + kvh) * 2048 * 128;

  bf16x8 qf[4];
#pragma unroll
  for (int ks = 0; ks < 4; ++ks)
    qf[ks] = *(const bf16x8*)(Qb + (size_t)l16 * 128 + ks * 32 + lhi * 8);

  f32x4 oacc[8];
#pragma unroll
  for (int i = 0; i < 8; ++i) oacc[i] = (f32x4)0.0f;
  float mrow[4], lrow[4];
#pragma unroll
  for (int r = 0; r < 4; ++r) { mrow[r] = -3.0e38f; lrow[r] = 0.0f; }

  for (int kt = 0; kt <= qt; ++kt) {
    const int t0 = kt * 64;
    __syncthreads();
    // stage K tile [64][128] linear
#pragma unroll
    for (int j = 0; j < 4; ++j) {
      int c = tid + j * 256;
      gload_lds16(Kb + (size_t)(t0 + (c >> 4)) * 128 + (c & 15) * 8,
                  Ks + (size_t)(wbase + j * 256) * 8);
    }
    // stage V transposed: [d][kv] with kv-pairs packed as dword writes
#pragma unroll
    for (int j = 0; j < 2; ++j) {
      int pc = tid + j * 256;
      int kp = pc >> 4, dc = (pc & 15) * 8;
      const u16* g = Vb + (size_t)(t0 + kp * 2) * 128 + dc;
      bf16x8 v0 = *(const bf16x8*)g;
      bf16x8 v1 = *(const bf16x8*)(g + 128);
#pragma unroll
      for (int e = 0; e < 8; ++e) {
        unsigned val = ((unsigned)(u16)v1[e] << 16) | (unsigned)(u16)v0[e];
        *(unsigned*)&VT[(dc + e) * 72 + kp * 2] = val;
      }
    }
    __syncthreads();

    // S = Q K^T (pre-scaled): wave's 16 q-rows x 64 kv
    f32x4 sacc[4];
#pragma unroll
    for (int ni = 0; ni < 4; ++ni) sacc[ni] = (f32x4)0.0f;
#pragma unroll
    for (int ks = 0; ks < 4; ++ks)
#pragma unroll
      for (int ni = 0; ni < 4; ++ni) {
        bf16x8 kf = *(const bf16x8*)&Ks[(ni * 16 + l16) * 128 + ks * 32 + lhi * 8];
        sacc[ni] = __builtin_amdgcn_mfma_f32_16x16x32_bf16(qf[ks], kf, sacc[ni], 0, 0, 0);
      }

    if (kt == qt) {  // diagonal tile: causal mask (q0 == t0)
#pragma unroll
      for (int ni = 0; ni < 4; ++ni)
#pragma unroll
        for (int r = 0; r < 4; ++r) {
          int qrow = w * 16 + lhi * 4 + r;
          int kcol = ni * 16 + l16;
          if (kcol > qrow) sacc[ni][r] = -3.0e38f;
        }
    }

    // online softmax (base-2; scale folded into Q)
    float mnew[4], sc[4];
#pragma unroll
    for (int r = 0; r < 4; ++r) {
      float rm = fmaxf(fmaxf(sacc[0][r], sacc[1][r]), fmaxf(sacc[2][r], sacc[3][r]));
      rm = fmaxf(rm, __shfl_xor(rm, 1));
      rm = fmaxf(rm, __shfl_xor(rm, 2));
      rm = fmaxf(rm, __shfl_xor(rm, 4));
      rm = fmaxf(rm, __shfl_xor(rm, 8));
      mnew[r] = fmaxf(mrow[r], rm);
      sc[r] = exp2f(mrow[r] - mnew[r]);
      mrow[r] = mnew[r];
    }
    float rs[4] = {0.f, 0.f, 0.f, 0.f};
#pragma unroll
    for (int ni = 0; ni < 4; ++ni)
#pragma unroll
      for (int r = 0; r < 4; ++r) {
        float p = exp2f(sacc[ni][r] - mnew[r]);
        rs[r] += p;
        PO[w][(lhi * 4 + r) * 72 + ni * 16 + l16] = f2bf(p);
      }
#pragma unroll
    for (int r = 0; r < 4; ++r) {
      float s2 = rs[r];
      s2 += __shfl_xor(s2, 1);
      s2 += __shfl_xor(s2, 2);
      s2 += __shfl_xor(s2, 4);
      s2 += __shfl_xor(s2, 8);
      lrow[r] = lrow[r] * sc[r] + s2;
    }
#pragma unroll
    for (int i = 0; i < 8; ++i)
#pragma unroll
      for (int r = 0; r < 4; ++r) oacc[i][r] *= sc[r];
    __syncthreads();

    // O += P V
#pragma unroll
    for (int ks = 0; ks < 2; ++ks) {
      bf16x8 pa = *(const bf16x8*)&PO[w][l16 * 72 + ks * 32 + lhi * 8];
#pragma unroll
      for (int nf = 0; nf < 8; ++nf) {
        bf16x8 vb = *(const bf16x8*)&VT[(nf * 16 + l16) * 72 + ks * 32 + lhi * 8];
        oacc[nf] = __builtin_amdgcn_mfma_f32_16x16x32_bf16(pa, vb, oacc[nf], 0, 0, 0);
      }
    }
  }

  // normalize, stage through LDS, coalesced store to (b, t, h*D+d)
  float inv[4];
#pragma unroll
  for (int r = 0; r < 4; ++r) inv[r] = 1.0f / lrow[r];
  __syncthreads();
#pragma unroll
  for (int nf = 0; nf < 8; ++nf)
#pragma unroll
    for (int r = 0; r < 4; ++r)
      PO[w][(lhi * 4 + r) * 128 + nf * 16 + l16] = f2bf(oacc[nf][r] * inv[r]);
  __syncthreads();
  u16* Ob = O + ((size_t)(b * 2048 + q0 + w * 16)) * 2048 + h * 128;
#pragma unroll
  for (int j = 0; j < 4; ++j) {
    int c = lane + j * 64;
    int row = c >> 4, dc = (c & 15) * 8;
    *(bf16x8*)(Ob + (size_t)row * 2048 + dc) = *(const bf16x8*)&PO[w][row * 128 + dc];
  }
}

extern "C" void kernel_launch(void* const* d_in, const int* in_sizes, int n_in,
                              void* d_out, int out_size, void* d_ws, size_t ws_size,
                              hipStream_t stream) {
  (void)in_sizes; (void)n_in; (void)out_size; (void)ws_size;
  const float* x    = (const float*)d_in[0];
  const float* Wq   = (const float*)d_in[1];
  const float* Wk   = (const float*)d_in[2];
  const float* Wv   = (const float*)d_in[3];
  const float* Wo   = (const float*)d_in[4];
  const float* cosp = (const float*)d_in[5];
  const float* sinp = (const float*)d_in[6];

  u16* ws  = (u16*)d_ws;
  u16* xbf = ws;               // 16,777,216 elems (B*T x C)  -- reused as attn out
  u16* Wqb = xbf + 16777216;   //  4,194,304
  u16* Wkb = Wqb + 4194304;    //  1,048,576
  u16* Wvb = Wkb + 1048576;    //  1,048,576
  u16* Wob = Wvb + 1048576;    //  4,194,304
  u16* Qb  = Wob + 4194304;    // 16,777,216 (B,H,T,D)
  u16* Kb  = Qb + 16777216;    //  4,194,304 (B,HKV,T,D)
  u16* Vb  = Kb + 4194304;     //  4,194,304
  u16* AO  = xbf;              // attention output (B,T,C), reuses x region

  cast_bf16_kernel<<<2048, 256, 0, stream>>>(x,  xbf, 16777216L);
  cast_bf16_kernel<<<512,  256, 0, stream>>>(Wq, Wqb, 4194304L);
  cast_bf16_kernel<<<256,  256, 0, stream>>>(Wk, Wkb, 1048576L);
  cast_bf16_kernel<<<256,  256, 0, stream>>>(Wv, Wvb, 1048576L);
  cast_bf16_kernel<<<512,  256, 0, stream>>>(Wo, Wob, 4194304L);

  const float qscale = (float)(1.4426950408889634 / sqrt(128.0));

  gemm_bt<0><<<dim3(16, 64), 256, 0, stream>>>(xbf, Wqb, Qb, 8192, 2048, 2048, cosp, sinp, qscale);
  gemm_bt<0><<<dim3(4,  64), 256, 0, stream>>>(xbf, Wkb, Kb, 8192, 512,  2048, cosp, sinp, 1.0f);
  gemm_bt<1><<<dim3(4,  64), 256, 0, stream>>>(xbf, Wvb, Vb, 8192, 512,  2048, cosp, sinp, 1.0f);

  attn_kernel<<<2048, 256, 0, stream>>>(Qb, Kb, Vb, AO);

  gemm_bt<2><<<dim3(16, 64), 256, 0, stream>>>(AO, Wob, d_out, 8192, 2048, 2048, nullptr, nullptr, 1.0f);
}

// Round 4
// 591.024 us; speedup vs baseline: 1.7739x; 1.7739x over previous
//
#include <hip/hip_runtime.h>
#include <cmath>

typedef __attribute__((ext_vector_type(8))) short bf16x8;
typedef __attribute__((ext_vector_type(4))) float f32x4;
typedef unsigned short u16;

__device__ __forceinline__ u16 f2bf(float f) {
  union { float f; unsigned u; } x; x.f = f;
  return (u16)((x.u + 0x7FFFu + ((x.u >> 16) & 1u)) >> 16);
}

__device__ __forceinline__ void gload_lds16(const void* g, void* l) {
  __builtin_amdgcn_global_load_lds((const __attribute__((address_space(1))) unsigned*)g,
                                   (__attribute__((address_space(3))) unsigned*)l,
                                   16, 0, 0);
}

__global__ __launch_bounds__(256) void cast_bf16_kernel(const float* __restrict__ in,
                                                        u16* __restrict__ out, long n) {
  long i = (long)blockIdx.x * blockDim.x + threadIdx.x;
  long stride = (long)gridDim.x * blockDim.x;
  for (long j = i * 4; j < n; j += stride * 4) {
    float4 v = *(const float4*)(in + j);
    ushort4 o;
    o.x = f2bf(v.x); o.y = f2bf(v.y); o.z = f2bf(v.z); o.w = f2bf(v.w);
    *(ushort4*)(out + j) = o;
  }
}

// C = A[M,K] * B[N,K]^T, bf16 inputs, f32 accumulate.
// EPI 0: RoPE + scale, write bf16 to (b, h, t, d) layout (tile col range == one head)
// EPI 1: plain bf16 write to (b, h, t, d)
// EPI 2: plain f32 write to [M, N]
template <int EPI>
__global__ __launch_bounds__(256) void gemm_bt(const u16* __restrict__ A,
                                               const u16* __restrict__ B,
                                               void* __restrict__ outp,
                                               int M, int N, int K,
                                               const float* __restrict__ cosp,
                                               const float* __restrict__ sinp,
                                               float scale) {
  __shared__ u16 As[128 * 64];
  __shared__ u16 Bs[128 * 64];
  const int tid = threadIdx.x;
  const int lane = tid & 63;
  const int l16 = lane & 15, lhi = lane >> 4;
  const int w = tid >> 6;
  const int wr = w >> 1, wc = w & 1;
  const int m0 = blockIdx.y * 128;
  const int n0 = blockIdx.x * 128;
  const int wbase = tid - lane;

  f32x4 acc[4][4];
#pragma unroll
  for (int i = 0; i < 4; ++i)
#pragma unroll
    for (int j = 0; j < 4; ++j) acc[i][j] = (f32x4)0.0f;

  for (int k0 = 0; k0 < K; k0 += 64) {
    __syncthreads();
#pragma unroll
    for (int j = 0; j < 4; ++j) {
      int c = tid + j * 256;
      gload_lds16(A + (size_t)(m0 + (c >> 3)) * K + k0 + (c & 7) * 8,
                  As + (size_t)(wbase + j * 256) * 8);
    }
#pragma unroll
    for (int j = 0; j < 4; ++j) {
      int c = tid + j * 256;
      gload_lds16(B + (size_t)(n0 + (c >> 3)) * K + k0 + (c & 7) * 8,
                  Bs + (size_t)(wbase + j * 256) * 8);
    }
    __syncthreads();
#pragma unroll
    for (int kk = 0; kk < 64; kk += 32) {
      bf16x8 af[4], bfr[4];
#pragma unroll
      for (int mi = 0; mi < 4; ++mi)
        af[mi] = *(const bf16x8*)&As[(wr * 64 + mi * 16 + l16) * 64 + kk + lhi * 8];
#pragma unroll
      for (int ni = 0; ni < 4; ++ni)
        bfr[ni] = *(const bf16x8*)&Bs[(wc * 64 + ni * 16 + l16) * 64 + kk + lhi * 8];
#pragma unroll
      for (int mi = 0; mi < 4; ++mi)
#pragma unroll
        for (int ni = 0; ni < 4; ++ni)
          acc[mi][ni] = __builtin_amdgcn_mfma_f32_16x16x32_bf16(af[mi], bfr[ni], acc[mi][ni], 0, 0, 0);
    }
  }

  if (EPI == 2) {
    float* o = (float*)outp;
#pragma unroll
    for (int mi = 0; mi < 4; ++mi)
#pragma unroll
      for (int r = 0; r < 4; ++r) {
        int row = m0 + wr * 64 + mi * 16 + lhi * 4 + r;
#pragma unroll
        for (int ni = 0; ni < 4; ++ni) {
          int col = n0 + wc * 64 + ni * 16 + l16;
          o[(size_t)row * N + col] = acc[mi][ni][r];
        }
      }
  } else {
    u16* o = (u16*)outp;
    const int nheads = N >> 7;
    const int h = blockIdx.x;
#pragma unroll
    for (int mi = 0; mi < 4; ++mi)
#pragma unroll
      for (int r = 0; r < 4; ++r) {
        int row = m0 + wr * 64 + mi * 16 + lhi * 4 + r;
        int b = row >> 11;
        int t = row & 2047;
        size_t base = ((size_t)(b * nheads + h) * 2048 + t) * 128;
#pragma unroll
        for (int ni = 0; ni < 4; ++ni) {
          int d = wc * 64 + ni * 16 + l16;
          float v = acc[mi][ni][r];
          if (EPI == 0) {
            float p = __shfl_xor(v, 1);
            float c = cosp[t * 64 + (d >> 1)];
            float s = sinp[t * 64 + (d >> 1)];
            v = (lane & 1) ? fmaf(p, s, v * c) : fmaf(v, c, -p * s);
            v *= scale;
          }
          o[base + d] = f2bf(v);
        }
      }
  }
}

// Flash attention: Q (B,H,T,D) bf16, K/V (B,HKV,T,D) bf16 -> O (B,T,H*D) bf16.
// Block = (b, h, 64-row q tile); 4 waves x 16 q-rows. 1/sqrt(D)*log2(e) pre-folded into Q.
// Ks: XOR-swizzled (key (row&7)<<4 bytes) staged via pre-swizzled global source, linear LDS dest.
// VT: V transposed [d][kv] stride 72, reg-staged packed-dword writes with e-rotation
//     (per-instruction banks = 4e+kp span all 32, 2 lanes each -> conflict-free).
// P ([16][72] per wave) and O-staging overlay the Ks region (barrier-protected).
// LDS total 34 KB -> 4 blocks/CU.
__global__ __launch_bounds__(256, 4) void attn_kernel(const u16* __restrict__ Q,
                                                      const u16* __restrict__ Kp,
                                                      const u16* __restrict__ Vp,
                                                      u16* __restrict__ O) {
  __shared__ u16 Ks[64 * 128];   // 16KB; P overlay (w*1152), O staging (w*2048)
  __shared__ u16 VT[128 * 72];   // 18KB: V transposed [d][kv], +8 pad

  const int tid = threadIdx.x;
  const int lane = tid & 63;
  const int w = tid >> 6;
  const int l16 = lane & 15, lhi = lane >> 4;
  const int bid = blockIdx.x;
  const int qt = 31 - (bid >> 6);      // heavy q-tiles dispatched first (LPT)
  const int hb = bid & 63;
  const int h = hb >> 2;
  const int b = hb & 3;
  const int kvh = h >> 2;
  const int q0 = qt * 64;
  const int wbase = tid - lane;

  const u16* Qb = Q + ((size_t)((b * 16 + h) * 2048 + q0 + w * 16)) * 128;
  const u16* Kb = Kp + (size_t)(b * 4 + kvh) * 2048 * 128;
  const u16* Vb = Vp + (size_t)(b * 4 + kvh) * 2048 * 128;

  u16* PP = Ks + w * 1152;  // per-wave P [16][72] overlay

  bf16x8 qf[4];
#pragma unroll
  for (int ks = 0; ks < 4; ++ks)
    qf[ks] = *(const bf16x8*)(Qb + (size_t)l16 * 128 + ks * 32 + lhi * 8);

  f32x4 oacc[8];
#pragma unroll
  for (int i = 0; i < 8; ++i) oacc[i] = (f32x4)0.0f;
  float mrow[4], lrow[4];
#pragma unroll
  for (int r = 0; r < 4; ++r) { mrow[r] = -3.0e38f; lrow[r] = 0.0f; }

  for (int kt = 0; kt <= qt; ++kt) {
    const int t0 = kt * 64;
    __syncthreads();
    // stage K tile, XOR-swizzled via pre-swizzled global source (linear LDS dest)
#pragma unroll
    for (int j = 0; j < 4; ++j) {
      int c = tid + j * 256;
      int row = c >> 4;
      int sboff = ((c & 15) * 16) ^ ((row & 7) << 4);   // byte offset within row
      gload_lds16(Kb + (size_t)(t0 + row) * 128 + (sboff >> 1),
                  Ks + (size_t)(wbase + j * 256) * 8);
    }
    // stage V transposed: [d][kv] with kv-pairs packed as dword writes; e-rotation
#pragma unroll
    for (int j = 0; j < 2; ++j) {
      int pc = tid + j * 256;
      int kp = pc >> 4, dc = (pc & 15) * 8;
      const u16* g = Vb + (size_t)(t0 + kp * 2) * 128 + dc;
      bf16x8 v0 = *(const bf16x8*)g;
      bf16x8 v1 = *(const bf16x8*)(g + 128);
#pragma unroll
      for (int i = 0; i < 8; ++i) {
        int e = (i + (pc & 15)) & 7;
        unsigned val = ((unsigned)(u16)v1[e] << 16) | (unsigned)(u16)v0[e];
        *(unsigned*)&VT[(dc + e) * 72 + kp * 2] = val;
      }
    }
    __syncthreads();

    // S = Q K^T (pre-scaled): wave's 16 q-rows x 64 kv, swizzled Ks read
    f32x4 sacc[4];
#pragma unroll
    for (int ni = 0; ni < 4; ++ni) sacc[ni] = (f32x4)0.0f;
    const char* ksb = (const char*)Ks;
#pragma unroll
    for (int ks = 0; ks < 4; ++ks)
#pragma unroll
      for (int ni = 0; ni < 4; ++ni) {
        int row = ni * 16 + l16;
        int boff = row * 256 + ((ks * 64 + lhi * 16) ^ ((l16 & 7) << 4));
        bf16x8 kf = *(const bf16x8*)(ksb + boff);
        sacc[ni] = __builtin_amdgcn_mfma_f32_16x16x32_bf16(qf[ks], kf, sacc[ni], 0, 0, 0);
      }

    if (kt == qt) {  // diagonal tile: causal mask (q0 == t0)
#pragma unroll
      for (int ni = 0; ni < 4; ++ni)
#pragma unroll
        for (int r = 0; r < 4; ++r) {
          int qrow = w * 16 + lhi * 4 + r;
          int kcol = ni * 16 + l16;
          if (kcol > qrow) sacc[ni][r] = -3.0e38f;
        }
    }

    __syncthreads();  // all waves done reading Ks before P overlay writes

    // online softmax (base-2; scale folded into Q)
    float mnew[4], sc[4];
#pragma unroll
    for (int r = 0; r < 4; ++r) {
      float rm = fmaxf(fmaxf(sacc[0][r], sacc[1][r]), fmaxf(sacc[2][r], sacc[3][r]));
      rm = fmaxf(rm, __shfl_xor(rm, 1));
      rm = fmaxf(rm, __shfl_xor(rm, 2));
      rm = fmaxf(rm, __shfl_xor(rm, 4));
      rm = fmaxf(rm, __shfl_xor(rm, 8));
      mnew[r] = fmaxf(mrow[r], rm);
      sc[r] = exp2f(mrow[r] - mnew[r]);
      mrow[r] = mnew[r];
    }
    float rs[4] = {0.f, 0.f, 0.f, 0.f};
#pragma unroll
    for (int ni = 0; ni < 4; ++ni)
#pragma unroll
      for (int r = 0; r < 4; ++r) {
        float p = exp2f(sacc[ni][r] - mnew[r]);
        rs[r] += p;
        PP[(lhi * 4 + r) * 72 + ni * 16 + l16] = f2bf(p);
      }
#pragma unroll
    for (int r = 0; r < 4; ++r) {
      float s2 = rs[r];
      s2 += __shfl_xor(s2, 1);
      s2 += __shfl_xor(s2, 2);
      s2 += __shfl_xor(s2, 4);
      s2 += __shfl_xor(s2, 8);
      lrow[r] = lrow[r] * sc[r] + s2;
    }
#pragma unroll
    for (int i = 0; i < 8; ++i)
#pragma unroll
      for (int r = 0; r < 4; ++r) oacc[i][r] *= sc[r];

    // O += P V
#pragma unroll
    for (int ks = 0; ks < 2; ++ks) {
      bf16x8 pa = *(const bf16x8*)&PP[l16 * 72 + ks * 32 + lhi * 8];
#pragma unroll
      for (int nf = 0; nf < 8; ++nf) {
        bf16x8 vb = *(const bf16x8*)&VT[(nf * 16 + l16) * 72 + ks * 32 + lhi * 8];
        oacc[nf] = __builtin_amdgcn_mfma_f32_16x16x32_bf16(pa, vb, oacc[nf], 0, 0, 0);
      }
    }
  }

  // normalize, stage through LDS (Ks region), coalesced store to (b, t, h*D+d)
  float inv[4];
#pragma unroll
  for (int r = 0; r < 4; ++r) inv[r] = 1.0f / lrow[r];
  __syncthreads();
  u16* OS = Ks + w * 2048;
#pragma unroll
  for (int nf = 0; nf < 8; ++nf)
#pragma unroll
    for (int r = 0; r < 4; ++r)
      OS[(lhi * 4 + r) * 128 + nf * 16 + l16] = f2bf(oacc[nf][r] * inv[r]);
  __syncthreads();
  u16* Ob = O + ((size_t)(b * 2048 + q0 + w * 16)) * 2048 + h * 128;
#pragma unroll
  for (int j = 0; j < 4; ++j) {
    int c = lane + j * 64;
    int row = c >> 4, dc = (c & 15) * 8;
    *(bf16x8*)(Ob + (size_t)row * 2048 + dc) = *(const bf16x8*)&OS[row * 128 + dc];
  }
}

extern "C" void kernel_launch(void* const* d_in, const int* in_sizes, int n_in,
                              void* d_out, int out_size, void* d_ws, size_t ws_size,
                              hipStream_t stream) {
  (void)in_sizes; (void)n_in; (void)out_size; (void)ws_size;
  const float* x    = (const float*)d_in[0];
  const float* Wq   = (const float*)d_in[1];
  const float* Wk   = (const float*)d_in[2];
  const float* Wv   = (const float*)d_in[3];
  const float* Wo   = (const float*)d_in[4];
  const float* cosp = (const float*)d_in[5];
  const float* sinp = (const float*)d_in[6];

  u16* ws  = (u16*)d_ws;
  u16* xbf = ws;               // 16,777,216 elems (B*T x C)  -- reused as attn out
  u16* Wqb = xbf + 16777216;   //  4,194,304
  u16* Wkb = Wqb + 4194304;    //  1,048,576
  u16* Wvb = Wkb + 1048576;    //  1,048,576
  u16* Wob = Wvb + 1048576;    //  4,194,304
  u16* Qb  = Wob + 4194304;    // 16,777,216 (B,H,T,D)
  u16* Kb  = Qb + 16777216;    //  4,194,304 (B,HKV,T,D)
  u16* Vb  = Kb + 4194304;     //  4,194,304
  u16* AO  = xbf;              // attention output (B,T,C), reuses x region

  cast_bf16_kernel<<<2048, 256, 0, stream>>>(x,  xbf, 16777216L);
  cast_bf16_kernel<<<512,  256, 0, stream>>>(Wq, Wqb, 4194304L);
  cast_bf16_kernel<<<256,  256, 0, stream>>>(Wk, Wkb, 1048576L);
  cast_bf16_kernel<<<256,  256, 0, stream>>>(Wv, Wvb, 1048576L);
  cast_bf16_kernel<<<512,  256, 0, stream>>>(Wo, Wob, 4194304L);

  const float qscale = (float)(1.4426950408889634 / sqrt(128.0));

  gemm_bt<0><<<dim3(16, 64), 256, 0, stream>>>(xbf, Wqb, Qb, 8192, 2048, 2048, cosp, sinp, qscale);
  gemm_bt<0><<<dim3(4,  64), 256, 0, stream>>>(xbf, Wkb, Kb, 8192, 512,  2048, cosp, sinp, 1.0f);
  gemm_bt<1><<<dim3(4,  64), 256, 0, stream>>>(xbf, Wvb, Vb, 8192, 512,  2048, cosp, sinp, 1.0f);

  attn_kernel<<<2048, 256, 0, stream>>>(Qb, Kb, Vb, AO);

  gemm_bt<2><<<dim3(16, 64), 256, 0, stream>>>(AO, Wob, d_out, 8192, 2048, 2048, nullptr, nullptr, 1.0f);
}

// Round 5
// 548.511 us; speedup vs baseline: 1.9114x; 1.0775x over previous
//
#include <hip/hip_runtime.h>
#include <cmath>

typedef __attribute__((ext_vector_type(8))) short bf16x8;
typedef __attribute__((ext_vector_type(4))) float f32x4;
typedef unsigned short u16;

__device__ __forceinline__ u16 f2bf(float f) {
  union { float f; unsigned u; } x; x.f = f;
  return (u16)((x.u + 0x7FFFu + ((x.u >> 16) & 1u)) >> 16);
}

__device__ __forceinline__ void gload_lds16(const void* g, void* l) {
  __builtin_amdgcn_global_load_lds((const __attribute__((address_space(1))) unsigned*)g,
                                   (__attribute__((address_space(3))) unsigned*)l,
                                   16, 0, 0);
}

__global__ __launch_bounds__(256) void cast_bf16_kernel(const float* __restrict__ in,
                                                        u16* __restrict__ out, long n) {
  long i = (long)blockIdx.x * blockDim.x + threadIdx.x;
  long stride = (long)gridDim.x * blockDim.x;
  for (long j = i * 4; j < n; j += stride * 4) {
    float4 v = *(const float4*)(in + j);
    ushort4 o;
    o.x = f2bf(v.x); o.y = f2bf(v.y); o.z = f2bf(v.z); o.w = f2bf(v.w);
    *(ushort4*)(out + j) = o;
  }
}

// C = A[M,K] * B[N,K]^T, bf16 inputs, f32 accumulate.
// EPI 0: RoPE + scale, write bf16 to (b, h, t, d) layout (tile col range == one head)
// EPI 1: plain bf16 write to (b, h, t, d)
// EPI 2: plain f32 write to [M, N]
template <int EPI>
__global__ __launch_bounds__(256) void gemm_bt(const u16* __restrict__ A,
                                               const u16* __restrict__ B,
                                               void* __restrict__ outp,
                                               int M, int N, int K,
                                               const float* __restrict__ cosp,
                                               const float* __restrict__ sinp,
                                               float scale) {
  __shared__ u16 As[128 * 64];
  __shared__ u16 Bs[128 * 64];
  const int tid = threadIdx.x;
  const int lane = tid & 63;
  const int l16 = lane & 15, lhi = lane >> 4;
  const int w = tid >> 6;
  const int wr = w >> 1, wc = w & 1;
  const int m0 = blockIdx.y * 128;
  const int n0 = blockIdx.x * 128;
  const int wbase = tid - lane;

  f32x4 acc[4][4];
#pragma unroll
  for (int i = 0; i < 4; ++i)
#pragma unroll
    for (int j = 0; j < 4; ++j) acc[i][j] = (f32x4)0.0f;

  for (int k0 = 0; k0 < K; k0 += 64) {
    __syncthreads();
#pragma unroll
    for (int j = 0; j < 4; ++j) {
      int c = tid + j * 256;
      gload_lds16(A + (size_t)(m0 + (c >> 3)) * K + k0 + (c & 7) * 8,
                  As + (size_t)(wbase + j * 256) * 8);
    }
#pragma unroll
    for (int j = 0; j < 4; ++j) {
      int c = tid + j * 256;
      gload_lds16(B + (size_t)(n0 + (c >> 3)) * K + k0 + (c & 7) * 8,
                  Bs + (size_t)(wbase + j * 256) * 8);
    }
    __syncthreads();
#pragma unroll
    for (int kk = 0; kk < 64; kk += 32) {
      bf16x8 af[4], bfr[4];
#pragma unroll
      for (int mi = 0; mi < 4; ++mi)
        af[mi] = *(const bf16x8*)&As[(wr * 64 + mi * 16 + l16) * 64 + kk + lhi * 8];
#pragma unroll
      for (int ni = 0; ni < 4; ++ni)
        bfr[ni] = *(const bf16x8*)&Bs[(wc * 64 + ni * 16 + l16) * 64 + kk + lhi * 8];
#pragma unroll
      for (int mi = 0; mi < 4; ++mi)
#pragma unroll
        for (int ni = 0; ni < 4; ++ni)
          acc[mi][ni] = __builtin_amdgcn_mfma_f32_16x16x32_bf16(af[mi], bfr[ni], acc[mi][ni], 0, 0, 0);
    }
  }

  if (EPI == 2) {
    float* o = (float*)outp;
#pragma unroll
    for (int mi = 0; mi < 4; ++mi)
#pragma unroll
      for (int r = 0; r < 4; ++r) {
        int row = m0 + wr * 64 + mi * 16 + lhi * 4 + r;
#pragma unroll
        for (int ni = 0; ni < 4; ++ni) {
          int col = n0 + wc * 64 + ni * 16 + l16;
          o[(size_t)row * N + col] = acc[mi][ni][r];
        }
      }
  } else {
    u16* o = (u16*)outp;
    const int nheads = N >> 7;
    const int h = blockIdx.x;
#pragma unroll
    for (int mi = 0; mi < 4; ++mi)
#pragma unroll
      for (int r = 0; r < 4; ++r) {
        int row = m0 + wr * 64 + mi * 16 + lhi * 4 + r;
        int b = row >> 11;
        int t = row & 2047;
        size_t base = ((size_t)(b * nheads + h) * 2048 + t) * 128;
#pragma unroll
        for (int ni = 0; ni < 4; ++ni) {
          int d = wc * 64 + ni * 16 + l16;
          float v = acc[mi][ni][r];
          if (EPI == 0) {
            float p = __shfl_xor(v, 1);
            float c = cosp[t * 64 + (d >> 1)];
            float s = sinp[t * 64 + (d >> 1)];
            v = (lane & 1) ? fmaf(p, s, v * c) : fmaf(v, c, -p * s);
            v *= scale;
          }
          o[base + d] = f2bf(v);
        }
      }
  }
}

// Flash attention: Q (B,H,T,D) bf16, K/V (B,HKV,T,D) bf16 -> O (B,T,H*D) bf16.
// Block = (b, h, 128-row q tile); 8 waves x 16 q-rows; KV tile = 64.
// 1/sqrt(D)*log2(e) pre-folded into Q.
// Ks: XOR-swizzled (key (row&7)<<4 bytes) staged via pre-swizzled global source.
// VT: V transposed [d][kv] stride 72, reg-staged packed-dword writes with e-rotation.
// Pb: per-wave P [16][72] in its OWN region (wave-private round trip -> no extra barrier).
// Wave-level causal guard skips fully-masked tiles; defer-max (THR=8) skips most rescales.
// LDS 52KB -> 3 blocks/CU (24 waves/CU).
__global__ __launch_bounds__(512, 4) void attn_kernel(const u16* __restrict__ Q,
                                                      const u16* __restrict__ Kp,
                                                      const u16* __restrict__ Vp,
                                                      u16* __restrict__ O) {
  __shared__ u16 lds[26624];          // 52KB total
  u16* Ks = lds;                      // [64][128] swizzled          (8192)
  u16* VT = lds + 8192;               // [128][72] V^T               (9216)
  u16* Pb = lds + 17408;              // 8 x [16][72] per-wave P     (9216)

  const int tid = threadIdx.x;
  const int lane = tid & 63;
  const int w = tid >> 6;
  const int l16 = lane & 15, lhi = lane >> 4;
  const int bid = blockIdx.x;
  const int qt = 15 - (bid >> 6);      // heavy q-tiles dispatched first (LPT)
  const int hb = bid & 63;
  const int h = hb >> 2;
  const int b = hb & 3;
  const int kvh = h >> 2;
  const int q0 = qt * 128;
  const int wbase = tid - lane;
  const int wrow0 = q0 + w * 16;       // this wave's first q row

  const u16* Qb = Q + ((size_t)((b * 16 + h) * 2048 + wrow0)) * 128;
  const u16* Kb = Kp + (size_t)(b * 4 + kvh) * 2048 * 128;
  const u16* Vb = Vp + (size_t)(b * 4 + kvh) * 2048 * 128;

  u16* PP = Pb + w * 1152;  // per-wave P [16][72]

  bf16x8 qf[4];
#pragma unroll
  for (int ks = 0; ks < 4; ++ks)
    qf[ks] = *(const bf16x8*)(Qb + (size_t)l16 * 128 + ks * 32 + lhi * 8);

  f32x4 oacc[8];
#pragma unroll
  for (int i = 0; i < 8; ++i) oacc[i] = (f32x4)0.0f;
  float mrow[4], lrow[4];
#pragma unroll
  for (int r = 0; r < 4; ++r) { mrow[r] = -3.0e38f; lrow[r] = 0.0f; }

  const int nkt = 2 * qt + 2;
  for (int kt = 0; kt < nkt; ++kt) {
    const int t0 = kt * 64;
    __syncthreads();
    // stage K tile, XOR-swizzled via pre-swizzled global source (linear LDS dest)
#pragma unroll
    for (int j = 0; j < 2; ++j) {
      int c = tid + j * 512;
      int row = c >> 4;
      int sboff = ((c & 15) * 16) ^ ((row & 7) << 4);   // byte offset within row
      gload_lds16(Kb + (size_t)(t0 + row) * 128 + (sboff >> 1),
                  Ks + (size_t)(wbase + j * 512) * 8);
    }
    // stage V transposed: [d][kv] kv-pairs packed as dwords; e-rotation for bank spread
    {
      int kp = tid >> 4, dc = (tid & 15) * 8;
      const u16* g = Vb + (size_t)(t0 + kp * 2) * 128 + dc;
      bf16x8 v0 = *(const bf16x8*)g;
      bf16x8 v1 = *(const bf16x8*)(g + 128);
#pragma unroll
      for (int i = 0; i < 8; ++i) {
        int e = (i + (tid & 15)) & 7;
        unsigned val = ((unsigned)(u16)v1[e] << 16) | (unsigned)(u16)v0[e];
        *(unsigned*)&VT[(dc + e) * 72 + kp * 2] = val;
      }
    }
    __syncthreads();

    if (t0 <= wrow0 + 15) {   // wave-uniform: tile has at least one unmasked column
      // S = Q K^T (pre-scaled): wave's 16 q-rows x 64 kv, swizzled Ks read
      f32x4 sacc[4];
#pragma unroll
      for (int ni = 0; ni < 4; ++ni) sacc[ni] = (f32x4)0.0f;
      const char* ksb = (const char*)Ks;
#pragma unroll
      for (int ks = 0; ks < 4; ++ks)
#pragma unroll
        for (int ni = 0; ni < 4; ++ni) {
          int row = ni * 16 + l16;
          int boff = row * 256 + ((ks * 64 + lhi * 16) ^ ((l16 & 7) << 4));
          bf16x8 kf = *(const bf16x8*)(ksb + boff);
          sacc[ni] = __builtin_amdgcn_mfma_f32_16x16x32_bf16(qf[ks], kf, sacc[ni], 0, 0, 0);
        }

      if (t0 + 63 > wrow0) {  // tile straddles the diagonal: elementwise causal mask
#pragma unroll
        for (int ni = 0; ni < 4; ++ni)
#pragma unroll
          for (int r = 0; r < 4; ++r) {
            int qrow = wrow0 + lhi * 4 + r;
            int kcol = t0 + ni * 16 + l16;
            if (kcol > qrow) sacc[ni][r] = -3.0e38f;
          }
      }

      // online softmax (base-2), defer-max: skip rescale when max growth <= 8
      float mnew[4];
      bool defer = true;
#pragma unroll
      for (int r = 0; r < 4; ++r) {
        float rm = fmaxf(fmaxf(sacc[0][r], sacc[1][r]), fmaxf(sacc[2][r], sacc[3][r]));
        rm = fmaxf(rm, __shfl_xor(rm, 1));
        rm = fmaxf(rm, __shfl_xor(rm, 2));
        rm = fmaxf(rm, __shfl_xor(rm, 4));
        rm = fmaxf(rm, __shfl_xor(rm, 8));
        mnew[r] = fmaxf(mrow[r], rm);
        defer = defer && (rm <= mrow[r] + 8.0f);
      }
      defer = __all(defer);
      if (defer) {
#pragma unroll
        for (int r = 0; r < 4; ++r) mnew[r] = mrow[r];
      } else {
#pragma unroll
        for (int r = 0; r < 4; ++r) {
          float sc = exp2f(mrow[r] - mnew[r]);
          mrow[r] = mnew[r];
          lrow[r] *= sc;
#pragma unroll
          for (int i = 0; i < 8; ++i) oacc[i][r] *= sc;
        }
      }
      float rs[4] = {0.f, 0.f, 0.f, 0.f};
#pragma unroll
      for (int ni = 0; ni < 4; ++ni)
#pragma unroll
        for (int r = 0; r < 4; ++r) {
          float p = exp2f(sacc[ni][r] - mnew[r]);
          rs[r] += p;
          PP[(lhi * 4 + r) * 72 + ni * 16 + l16] = f2bf(p);
        }
#pragma unroll
      for (int r = 0; r < 4; ++r) {
        float s2 = rs[r];
        s2 += __shfl_xor(s2, 1);
        s2 += __shfl_xor(s2, 2);
        s2 += __shfl_xor(s2, 4);
        s2 += __shfl_xor(s2, 8);
        lrow[r] += s2;
      }

      // O += P V  (wave-private P round trip; VT read stride-72 conflict-free)
#pragma unroll
      for (int ks = 0; ks < 2; ++ks) {
        bf16x8 pa = *(const bf16x8*)&PP[l16 * 72 + ks * 32 + lhi * 8];
#pragma unroll
        for (int nf = 0; nf < 8; ++nf) {
          bf16x8 vb = *(const bf16x8*)&VT[(nf * 16 + l16) * 72 + ks * 32 + lhi * 8];
          oacc[nf] = __builtin_amdgcn_mfma_f32_16x16x32_bf16(pa, vb, oacc[nf], 0, 0, 0);
        }
      }
    }
  }

  // normalize, stage through LDS (Ks+VT region), coalesced store to (b, t, h*D+d)
  float inv[4];
#pragma unroll
  for (int r = 0; r < 4; ++r) inv[r] = 1.0f / lrow[r];
  __syncthreads();
  u16* OS = lds + w * 2048;
#pragma unroll
  for (int nf = 0; nf < 8; ++nf)
#pragma unroll
    for (int r = 0; r < 4; ++r)
      OS[(lhi * 4 + r) * 128 + nf * 16 + l16] = f2bf(oacc[nf][r] * inv[r]);
  __syncthreads();
  u16* Ob = O + ((size_t)(b * 2048 + wrow0)) * 2048 + h * 128;
#pragma unroll
  for (int j = 0; j < 4; ++j) {
    int c = lane + j * 64;
    int row = c >> 4, dc = (c & 15) * 8;
    *(bf16x8*)(Ob + (size_t)row * 2048 + dc) = *(const bf16x8*)&OS[row * 128 + dc];
  }
}

extern "C" void kernel_launch(void* const* d_in, const int* in_sizes, int n_in,
                              void* d_out, int out_size, void* d_ws, size_t ws_size,
                              hipStream_t stream) {
  (void)in_sizes; (void)n_in; (void)out_size; (void)ws_size;
  const float* x    = (const float*)d_in[0];
  const float* Wq   = (const float*)d_in[1];
  const float* Wk   = (const float*)d_in[2];
  const float* Wv   = (const float*)d_in[3];
  const float* Wo   = (const float*)d_in[4];
  const float* cosp = (const float*)d_in[5];
  const float* sinp = (const float*)d_in[6];

  u16* ws  = (u16*)d_ws;
  u16* xbf = ws;               // 16,777,216 elems (B*T x C)  -- reused as attn out
  u16* Wqb = xbf + 16777216;   //  4,194,304
  u16* Wkb = Wqb + 4194304;    //  1,048,576
  u16* Wvb = Wkb + 1048576;    //  1,048,576
  u16* Wob = Wvb + 1048576;    //  4,194,304
  u16* Qb  = Wob + 4194304;    // 16,777,216 (B,H,T,D)
  u16* Kb  = Qb + 16777216;    //  4,194,304 (B,HKV,T,D)
  u16* Vb  = Kb + 4194304;     //  4,194,304
  u16* AO  = xbf;              // attention output (B,T,C), reuses x region

  cast_bf16_kernel<<<2048, 256, 0, stream>>>(x,  xbf, 16777216L);
  cast_bf16_kernel<<<512,  256, 0, stream>>>(Wq, Wqb, 4194304L);
  cast_bf16_kernel<<<256,  256, 0, stream>>>(Wk, Wkb, 1048576L);
  cast_bf16_kernel<<<256,  256, 0, stream>>>(Wv, Wvb, 1048576L);
  cast_bf16_kernel<<<512,  256, 0, stream>>>(Wo, Wob, 4194304L);

  const float qscale = (float)(1.4426950408889634 / sqrt(128.0));

  gemm_bt<0><<<dim3(16, 64), 256, 0, stream>>>(xbf, Wqb, Qb, 8192, 2048, 2048, cosp, sinp, qscale);
  gemm_bt<0><<<dim3(4,  64), 256, 0, stream>>>(xbf, Wkb, Kb, 8192, 512,  2048, cosp, sinp, 1.0f);
  gemm_bt<1><<<dim3(4,  64), 256, 0, stream>>>(xbf, Wvb, Vb, 8192, 512,  2048, cosp, sinp, 1.0f);

  attn_kernel<<<1024, 512, 0, stream>>>(Qb, Kb, Vb, AO);

  gemm_bt<2><<<dim3(16, 64), 256, 0, stream>>>(AO, Wob, d_out, 8192, 2048, 2048, nullptr, nullptr, 1.0f);
}

// Round 6
// 462.228 us; speedup vs baseline: 2.2682x; 1.1867x over previous
//
#include <hip/hip_runtime.h>
#include <cmath>

typedef __attribute__((ext_vector_type(8))) short bf16x8;
typedef __attribute__((ext_vector_type(4))) float f32x4;
typedef unsigned short u16;

__device__ __forceinline__ u16 f2bf(float f) {
  union { float f; unsigned u; } x; x.f = f;
  return (u16)((x.u + 0x7FFFu + ((x.u >> 16) & 1u)) >> 16);
}

__device__ __forceinline__ void gload_lds16(const void* g, void* l) {
  __builtin_amdgcn_global_load_lds((const __attribute__((address_space(1))) unsigned*)g,
                                   (__attribute__((address_space(3))) unsigned*)l,
                                   16, 0, 0);
}

__global__ __launch_bounds__(256) void cast_bf16_kernel(const float* __restrict__ in,
                                                        u16* __restrict__ out, long n) {
  long i = (long)blockIdx.x * blockDim.x + threadIdx.x;
  long stride = (long)gridDim.x * blockDim.x;
  for (long j = i * 4; j < n; j += stride * 4) {
    float4 v = *(const float4*)(in + j);
    ushort4 o;
    o.x = f2bf(v.x); o.y = f2bf(v.y); o.z = f2bf(v.z); o.w = f2bf(v.w);
    *(ushort4*)(out + j) = o;
  }
}

// C = A[M,K] * B[N,K]^T, bf16 inputs, f32 accumulate.
// EPI 0: RoPE + scale, write bf16 to (b, h, t, d) layout (tile col range == one head)
// EPI 2: plain f32 write to [M, N]
// EPI 3: merged KV: blocks 0-3 = K heads (RoPE, (b,h,t,d)); blocks 4-7 = V heads,
//        written TRANSPOSED to vtp as (b, kvh, d, t).
template <int EPI>
__global__ __launch_bounds__(256) void gemm_bt(const u16* __restrict__ A,
                                               const u16* __restrict__ B,
                                               void* __restrict__ outp,
                                               u16* __restrict__ vtp,
                                               int M, int N, int K,
                                               const float* __restrict__ cosp,
                                               const float* __restrict__ sinp,
                                               float scale) {
  __shared__ u16 As[128 * 64];
  __shared__ u16 Bs[128 * 64];
  const int tid = threadIdx.x;
  const int lane = tid & 63;
  const int l16 = lane & 15, lhi = lane >> 4;
  const int w = tid >> 6;
  const int wr = w >> 1, wc = w & 1;
  const int m0 = blockIdx.y * 128;
  const int n0 = blockIdx.x * 128;
  const int wbase = tid - lane;

  f32x4 acc[4][4];
#pragma unroll
  for (int i = 0; i < 4; ++i)
#pragma unroll
    for (int j = 0; j < 4; ++j) acc[i][j] = (f32x4)0.0f;

  for (int k0 = 0; k0 < K; k0 += 64) {
    __syncthreads();
#pragma unroll
    for (int j = 0; j < 4; ++j) {
      int c = tid + j * 256;
      gload_lds16(A + (size_t)(m0 + (c >> 3)) * K + k0 + (c & 7) * 8,
                  As + (size_t)(wbase + j * 256) * 8);
    }
#pragma unroll
    for (int j = 0; j < 4; ++j) {
      int c = tid + j * 256;
      gload_lds16(B + (size_t)(n0 + (c >> 3)) * K + k0 + (c & 7) * 8,
                  Bs + (size_t)(wbase + j * 256) * 8);
    }
    __syncthreads();
#pragma unroll
    for (int kk = 0; kk < 64; kk += 32) {
      bf16x8 af[4], bfr[4];
#pragma unroll
      for (int mi = 0; mi < 4; ++mi)
        af[mi] = *(const bf16x8*)&As[(wr * 64 + mi * 16 + l16) * 64 + kk + lhi * 8];
#pragma unroll
      for (int ni = 0; ni < 4; ++ni)
        bfr[ni] = *(const bf16x8*)&Bs[(wc * 64 + ni * 16 + l16) * 64 + kk + lhi * 8];
#pragma unroll
      for (int mi = 0; mi < 4; ++mi)
#pragma unroll
        for (int ni = 0; ni < 4; ++ni)
          acc[mi][ni] = __builtin_amdgcn_mfma_f32_16x16x32_bf16(af[mi], bfr[ni], acc[mi][ni], 0, 0, 0);
    }
  }

  if (EPI == 2) {
    float* o = (float*)outp;
#pragma unroll
    for (int mi = 0; mi < 4; ++mi)
#pragma unroll
      for (int r = 0; r < 4; ++r) {
        int row = m0 + wr * 64 + mi * 16 + lhi * 4 + r;
#pragma unroll
        for (int ni = 0; ni < 4; ++ni) {
          int col = n0 + wc * 64 + ni * 16 + l16;
          o[(size_t)row * N + col] = acc[mi][ni][r];
        }
      }
  } else if (EPI == 0) {
    u16* o = (u16*)outp;
    const int nheads = N >> 7;
    const int h = blockIdx.x;
#pragma unroll
    for (int mi = 0; mi < 4; ++mi)
#pragma unroll
      for (int r = 0; r < 4; ++r) {
        int row = m0 + wr * 64 + mi * 16 + lhi * 4 + r;
        int b = row >> 11;
        int t = row & 2047;
        size_t base = ((size_t)(b * nheads + h) * 2048 + t) * 128;
#pragma unroll
        for (int ni = 0; ni < 4; ++ni) {
          int d = wc * 64 + ni * 16 + l16;
          float v = acc[mi][ni][r];
          float p = __shfl_xor(v, 1);
          float c = cosp[t * 64 + (d >> 1)];
          float s = sinp[t * 64 + (d >> 1)];
          v = (lane & 1) ? fmaf(p, s, v * c) : fmaf(v, c, -p * s);
          v *= scale;
          o[base + d] = f2bf(v);
        }
      }
  } else {  // EPI == 3: merged KV
    const int bx = blockIdx.x;
    if (bx < 4) {   // K head bx: RoPE (scale=1), (b, h=bx, t, d) layout
      u16* o = (u16*)outp;
#pragma unroll
      for (int mi = 0; mi < 4; ++mi)
#pragma unroll
        for (int r = 0; r < 4; ++r) {
          int row = m0 + wr * 64 + mi * 16 + lhi * 4 + r;
          int b = row >> 11;
          int t = row & 2047;
          size_t base = ((size_t)(b * 4 + bx) * 2048 + t) * 128;
#pragma unroll
          for (int ni = 0; ni < 4; ++ni) {
            int d = wc * 64 + ni * 16 + l16;
            float v = acc[mi][ni][r];
            float p = __shfl_xor(v, 1);
            float c = cosp[t * 64 + (d >> 1)];
            float s = sinp[t * 64 + (d >> 1)];
            v = (lane & 1) ? fmaf(p, s, v * c) : fmaf(v, c, -p * s);
            o[base + d] = f2bf(v);
          }
        }
    } else {        // V head (bx-4): write V^T (b, kvh, d, t)
      const int kvh = bx - 4;
#pragma unroll
      for (int mi = 0; mi < 4; ++mi)
#pragma unroll
        for (int r = 0; r < 4; ++r) {
          int row = m0 + wr * 64 + mi * 16 + lhi * 4 + r;
          int b = row >> 11;
          int t = row & 2047;
          size_t base = ((size_t)(b * 4 + kvh) * 128) * 2048 + t;
#pragma unroll
          for (int ni = 0; ni < 4; ++ni) {
            int d = wc * 64 + ni * 16 + l16;
            vtp[base + (size_t)d * 2048] = f2bf(acc[mi][ni][r]);
          }
        }
    }
  }
}

// Flash attention: Q (B,H,T,D) bf16, K (B,HKV,T,D) bf16, V^T (B,HKV,D,T) bf16
//   -> O (B,T,H*D) bf16.
// Block = (b, h, 128-row q tile); 8 waves x 16 q-rows; KV tile = 64.
// 1/sqrt(D)*log2(e) pre-folded into Q.
// Ks:  [64][128] XOR-swizzled (key (row&7)<<4 bytes), staged via pre-swizzled global source.
// VTs: [128][64] V^T tile, XOR-swizzled the same way, staged via 2 global_load_lds
//      (no reg-pack transpose -- V is already transposed in global).
// Pb:  per-wave P [16][72] (wave-private round trip, no extra barrier).
// Wave-level causal guard skips fully-masked tiles; defer-max (THR=8) skips most rescales.
// LDS 50KB -> 3 blocks/CU.
__global__ __launch_bounds__(512, 4) void attn_kernel(const u16* __restrict__ Q,
                                                      const u16* __restrict__ Kp,
                                                      const u16* __restrict__ Vtp,
                                                      u16* __restrict__ O) {
  __shared__ u16 lds[25600];          // 50KB total
  u16* Ks  = lds;                     // [64][128] swizzled          (8192)
  u16* VTs = lds + 8192;              // [128][64] swizzled V^T      (8192)
  u16* Pb  = lds + 16384;             // 8 x [16][72] per-wave P     (9216)

  const int tid = threadIdx.x;
  const int lane = tid & 63;
  const int w = tid >> 6;
  const int l16 = lane & 15, lhi = lane >> 4;
  const int bid = blockIdx.x;
  const int qt = 15 - (bid >> 6);      // heavy q-tiles dispatched first (LPT)
  const int hb = bid & 63;
  const int h = hb >> 2;
  const int b = hb & 3;
  const int kvh = h >> 2;
  const int q0 = qt * 128;
  const int wbase = tid - lane;
  const int wrow0 = q0 + w * 16;       // this wave's first q row

  const u16* Qb = Q + ((size_t)((b * 16 + h) * 2048 + wrow0)) * 128;
  const u16* Kb = Kp + (size_t)(b * 4 + kvh) * 2048 * 128;
  const u16* Vtb = Vtp + (size_t)(b * 4 + kvh) * 128 * 2048;

  u16* PP = Pb + w * 1152;  // per-wave P [16][72]

  bf16x8 qf[4];
#pragma unroll
  for (int ks = 0; ks < 4; ++ks)
    qf[ks] = *(const bf16x8*)(Qb + (size_t)l16 * 128 + ks * 32 + lhi * 8);

  f32x4 oacc[8];
#pragma unroll
  for (int i = 0; i < 8; ++i) oacc[i] = (f32x4)0.0f;
  float mrow[4], lrow[4];
#pragma unroll
  for (int r = 0; r < 4; ++r) { mrow[r] = -3.0e38f; lrow[r] = 0.0f; }

  const int nkt = 2 * qt + 2;
  for (int kt = 0; kt < nkt; ++kt) {
    const int t0 = kt * 64;
    __syncthreads();
    // stage K tile [64][128], XOR-swizzled via pre-swizzled global source
#pragma unroll
    for (int j = 0; j < 2; ++j) {
      int c = tid + j * 512;
      int row = c >> 4;
      int sboff = ((c & 15) * 16) ^ ((row & 7) << 4);   // byte offset within row
      gload_lds16(Kb + (size_t)(t0 + row) * 128 + (sboff >> 1),
                  Ks + (size_t)(wbase + j * 512) * 8);
    }
    // stage V^T tile [128][64], XOR-swizzled via pre-swizzled global source
#pragma unroll
    for (int j = 0; j < 2; ++j) {
      int c = tid + j * 512;
      int d = c >> 3;
      int sboff = ((c & 7) * 16) ^ ((d & 7) << 4);      // byte offset within row (128B)
      gload_lds16(Vtb + (size_t)d * 2048 + t0 + (sboff >> 1),
                  VTs + (size_t)(wbase + j * 512) * 8);
    }
    __syncthreads();

    if (t0 <= wrow0 + 15) {   // wave-uniform: tile has at least one unmasked column
      // S = Q K^T (pre-scaled): wave's 16 q-rows x 64 kv, swizzled Ks read
      f32x4 sacc[4];
#pragma unroll
      for (int ni = 0; ni < 4; ++ni) sacc[ni] = (f32x4)0.0f;
      const char* ksb = (const char*)Ks;
#pragma unroll
      for (int ks = 0; ks < 4; ++ks)
#pragma unroll
        for (int ni = 0; ni < 4; ++ni) {
          int row = ni * 16 + l16;
          int boff = row * 256 + ((ks * 64 + lhi * 16) ^ ((l16 & 7) << 4));
          bf16x8 kf = *(const bf16x8*)(ksb + boff);
          sacc[ni] = __builtin_amdgcn_mfma_f32_16x16x32_bf16(qf[ks], kf, sacc[ni], 0, 0, 0);
        }

      if (t0 + 63 > wrow0) {  // tile straddles the diagonal: elementwise causal mask
#pragma unroll
        for (int ni = 0; ni < 4; ++ni)
#pragma unroll
          for (int r = 0; r < 4; ++r) {
            int qrow = wrow0 + lhi * 4 + r;
            int kcol = t0 + ni * 16 + l16;
            if (kcol > qrow) sacc[ni][r] = -3.0e38f;
          }
      }

      // online softmax (base-2), defer-max: skip rescale when max growth <= 8
      float mnew[4];
      bool defer = true;
#pragma unroll
      for (int r = 0; r < 4; ++r) {
        float rm = fmaxf(fmaxf(sacc[0][r], sacc[1][r]), fmaxf(sacc[2][r], sacc[3][r]));
        rm = fmaxf(rm, __shfl_xor(rm, 1));
        rm = fmaxf(rm, __shfl_xor(rm, 2));
        rm = fmaxf(rm, __shfl_xor(rm, 4));
        rm = fmaxf(rm, __shfl_xor(rm, 8));
        mnew[r] = fmaxf(mrow[r], rm);
        defer = defer && (rm <= mrow[r] + 8.0f);
      }
      defer = __all(defer);
      if (defer) {
#pragma unroll
        for (int r = 0; r < 4; ++r) mnew[r] = mrow[r];
      } else {
#pragma unroll
        for (int r = 0; r < 4; ++r) {
          float sc = exp2f(mrow[r] - mnew[r]);
          mrow[r] = mnew[r];
          lrow[r] *= sc;
#pragma unroll
          for (int i = 0; i < 8; ++i) oacc[i][r] *= sc;
        }
      }
      float rs[4] = {0.f, 0.f, 0.f, 0.f};
#pragma unroll
      for (int ni = 0; ni < 4; ++ni)
#pragma unroll
        for (int r = 0; r < 4; ++r) {
          float p = exp2f(sacc[ni][r] - mnew[r]);
          rs[r] += p;
          PP[(lhi * 4 + r) * 72 + ni * 16 + l16] = f2bf(p);
        }
#pragma unroll
      for (int r = 0; r < 4; ++r) {
        float s2 = rs[r];
        s2 += __shfl_xor(s2, 1);
        s2 += __shfl_xor(s2, 2);
        s2 += __shfl_xor(s2, 4);
        s2 += __shfl_xor(s2, 8);
        lrow[r] += s2;
      }

      // O += P V : B-fragment = V^T[d = nf*16+l16][t0 + ks*32 + lhi*8 ..], swizzled VTs read
      const char* vtb = (const char*)VTs;
#pragma unroll
      for (int ks = 0; ks < 2; ++ks) {
        bf16x8 pa = *(const bf16x8*)&PP[l16 * 72 + ks * 32 + lhi * 8];
#pragma unroll
        for (int nf = 0; nf < 8; ++nf) {
          int row = nf * 16 + l16;
          int boff = row * 128 + ((ks * 64 + lhi * 16) ^ ((l16 & 7) << 4));
          bf16x8 vb = *(const bf16x8*)(vtb + boff);
          oacc[nf] = __builtin_amdgcn_mfma_f32_16x16x32_bf16(pa, vb, oacc[nf], 0, 0, 0);
        }
      }
    }
  }

  // normalize, stage through LDS (Ks+VTs region), coalesced store to (b, t, h*D+d)
  float inv[4];
#pragma unroll
  for (int r = 0; r < 4; ++r) inv[r] = 1.0f / lrow[r];
  __syncthreads();
  u16* OS = lds + w * 2048;
#pragma unroll
  for (int nf = 0; nf < 8; ++nf)
#pragma unroll
    for (int r = 0; r < 4; ++r)
      OS[(lhi * 4 + r) * 128 + nf * 16 + l16] = f2bf(oacc[nf][r] * inv[r]);
  __syncthreads();
  u16* Ob = O + ((size_t)(b * 2048 + wrow0)) * 2048 + h * 128;
#pragma unroll
  for (int j = 0; j < 4; ++j) {
    int c = lane + j * 64;
    int row = c >> 4, dc = (c & 15) * 8;
    *(bf16x8*)(Ob + (size_t)row * 2048 + dc) = *(const bf16x8*)&OS[row * 128 + dc];
  }
}

extern "C" void kernel_launch(void* const* d_in, const int* in_sizes, int n_in,
                              void* d_out, int out_size, void* d_ws, size_t ws_size,
                              hipStream_t stream) {
  (void)in_sizes; (void)n_in; (void)out_size; (void)ws_size;
  const float* x    = (const float*)d_in[0];
  const float* Wq   = (const float*)d_in[1];
  const float* Wk   = (const float*)d_in[2];
  const float* Wv   = (const float*)d_in[3];
  const float* Wo   = (const float*)d_in[4];
  const float* cosp = (const float*)d_in[5];
  const float* sinp = (const float*)d_in[6];

  u16* ws  = (u16*)d_ws;
  u16* xbf = ws;               // 16,777,216 elems (B*T x C)  -- reused as attn out
  u16* Wqb = xbf + 16777216;   //  4,194,304
  u16* Wkb = Wqb + 4194304;    //  1,048,576  } contiguous 1024x2048 KV weight
  u16* Wvb = Wkb + 1048576;    //  1,048,576  }
  u16* Wob = Wvb + 1048576;    //  4,194,304
  u16* Qb  = Wob + 4194304;    // 16,777,216 (B,H,T,D)
  u16* Kb  = Qb + 16777216;    //  4,194,304 (B,HKV,T,D)
  u16* Vb  = Kb + 4194304;     //  4,194,304 (B,HKV,D,T)  == V^T
  u16* AO  = xbf;              // attention output (B,T,C), reuses x region

  cast_bf16_kernel<<<2048, 256, 0, stream>>>(x,  xbf, 16777216L);
  cast_bf16_kernel<<<512,  256, 0, stream>>>(Wq, Wqb, 4194304L);
  cast_bf16_kernel<<<256,  256, 0, stream>>>(Wk, Wkb, 1048576L);
  cast_bf16_kernel<<<256,  256, 0, stream>>>(Wv, Wvb, 1048576L);
  cast_bf16_kernel<<<512,  256, 0, stream>>>(Wo, Wob, 4194304L);

  const float qscale = (float)(1.4426950408889634 / sqrt(128.0));

  gemm_bt<0><<<dim3(16, 64), 256, 0, stream>>>(xbf, Wqb, Qb, nullptr, 8192, 2048, 2048, cosp, sinp, qscale);
  gemm_bt<3><<<dim3(8,  64), 256, 0, stream>>>(xbf, Wkb, Kb, Vb, 8192, 1024, 2048, cosp, sinp, 1.0f);

  attn_kernel<<<1024, 512, 0, stream>>>(Qb, Kb, Vb, AO);

  gemm_bt<2><<<dim3(16, 64), 256, 0, stream>>>(AO, Wob, d_out, nullptr, 8192, 2048, 2048, nullptr, nullptr, 1.0f);
}

// Round 7
// 391.007 us; speedup vs baseline: 2.6813x; 1.1821x over previous
//
#include <hip/hip_runtime.h>
#include <cmath>

typedef __attribute__((ext_vector_type(8))) short bf16x8;
typedef __attribute__((ext_vector_type(4))) float f32x4;
typedef unsigned short u16;

__device__ __forceinline__ u16 f2bf(float f) {
  union { float f; unsigned u; } x; x.f = f;
  return (u16)((x.u + 0x7FFFu + ((x.u >> 16) & 1u)) >> 16);
}

__device__ __forceinline__ void gload_lds16(const void* g, void* l) {
  __builtin_amdgcn_global_load_lds((const __attribute__((address_space(1))) unsigned*)g,
                                   (__attribute__((address_space(3))) unsigned*)l,
                                   16, 0, 0);
}

__global__ __launch_bounds__(256) void cast_bf16_kernel(const float* __restrict__ in,
                                                        u16* __restrict__ out, long n) {
  long i = (long)blockIdx.x * blockDim.x + threadIdx.x;
  long stride = (long)gridDim.x * blockDim.x;
  for (long j = i * 4; j < n; j += stride * 4) {
    float4 v = *(const float4*)(in + j);
    ushort4 o;
    o.x = f2bf(v.x); o.y = f2bf(v.y); o.z = f2bf(v.z); o.w = f2bf(v.w);
    *(ushort4*)(out + j) = o;
  }
}

// ---------------- 256x256 counted-vmcnt deep-pipeline GEMM ----------------
// C = A[M,K] * B[N,K]^T. 8 waves (2x4), BK=64, LDS 128KB double-buffer.
// Pipeline: stage t0,t1; iter t: vmcnt(8) [t's loads landed, t+1 in flight],
// barrier, 4 quadrant phases (T2-swizzled ds_read + 16 MFMA, setprio), lgkmcnt(0),
// barrier, stage t+2 into freed buffer. Never drains vmcnt mid-loop.
// EPI 0: RoPE + scale, bf16 to (b, h=col>>7, t, d=col&127). EPI 2: f32 [M,N].
template <int EPI>
__global__ __launch_bounds__(512, 2) void gemm_bt256(const u16* __restrict__ A,
                                                     const u16* __restrict__ B,
                                                     void* __restrict__ outp,
                                                     int M, int N, int K,
                                                     const float* __restrict__ cosp,
                                                     const float* __restrict__ sinp,
                                                     float scale) {
  __shared__ u16 lds[65536];   // [buf][A 256x64 | B 256x64], 128KB
  const int tid = threadIdx.x;
  const int lane = tid & 63;
  const int l16 = lane & 15, lhi = lane >> 4;
  const int w = tid >> 6;
  const int wr = w >> 2, wc = w & 3;          // wave tile: rows wr*128, cols wc*64
  const int m0 = blockIdx.y * 256;
  const int n0 = blockIdx.x * 256;

  f32x4 acc[8][4];
#pragma unroll
  for (int i = 0; i < 8; ++i)
#pragma unroll
    for (int j = 0; j < 4; ++j) acc[i][j] = (f32x4)0.0f;

  const int NT = K >> 6;

  auto stage = [&](int t, int buf) {
    const int k0 = t << 6;
    u16* Ad = lds + buf * 32768;
    u16* Bd = Ad + 16384;
#pragma unroll
    for (int j = 0; j < 4; ++j) {
      int c = tid + j * 512;
      int row = c >> 3;
      int sboff = ((c & 7) * 16) ^ ((row & 7) << 4);
      gload_lds16(A + (size_t)(m0 + row) * K + k0 + (sboff >> 1), Ad + (size_t)c * 8);
    }
#pragma unroll
    for (int j = 0; j < 4; ++j) {
      int c = tid + j * 512;
      int row = c >> 3;
      int sboff = ((c & 7) * 16) ^ ((row & 7) << 4);
      gload_lds16(B + (size_t)(n0 + row) * K + k0 + (sboff >> 1), Bd + (size_t)c * 8);
    }
  };

  stage(0, 0);
  stage(1, 1);

  for (int t = 0; t < NT; ++t) {
    const int cur = t & 1;
    if (t + 1 < NT) { asm volatile("s_waitcnt vmcnt(8)" ::: "memory"); }
    else            { asm volatile("s_waitcnt vmcnt(0)" ::: "memory"); }
    __builtin_amdgcn_s_barrier();      // buf[cur] fully staged by all waves
    const char* Ab = (const char*)(lds + cur * 32768);
    const char* Bb = (const char*)(lds + cur * 32768 + 16384);
#pragma unroll
    for (int qm = 0; qm < 2; ++qm)
#pragma unroll
      for (int qn = 0; qn < 2; ++qn) {
        bf16x8 af[4][2], bfr[2][2];
#pragma unroll
        for (int mi = 0; mi < 4; ++mi) {
          int ra = wr * 128 + qm * 64 + mi * 16 + l16;
#pragma unroll
          for (int kk = 0; kk < 2; ++kk)
            af[mi][kk] = *(const bf16x8*)(Ab + ra * 128 + ((kk * 64 + lhi * 16) ^ ((ra & 7) << 4)));
        }
#pragma unroll
        for (int ni = 0; ni < 2; ++ni) {
          int rb = wc * 64 + qn * 32 + ni * 16 + l16;
#pragma unroll
          for (int kk = 0; kk < 2; ++kk)
            bfr[ni][kk] = *(const bf16x8*)(Bb + rb * 128 + ((kk * 64 + lhi * 16) ^ ((rb & 7) << 4)));
        }
        __builtin_amdgcn_s_setprio(1);
#pragma unroll
        for (int kk = 0; kk < 2; ++kk)
#pragma unroll
          for (int mi = 0; mi < 4; ++mi)
#pragma unroll
            for (int ni = 0; ni < 2; ++ni)
              acc[qm * 4 + mi][qn * 2 + ni] = __builtin_amdgcn_mfma_f32_16x16x32_bf16(
                  af[mi][kk], bfr[ni][kk], acc[qm * 4 + mi][qn * 2 + ni], 0, 0, 0);
        __builtin_amdgcn_s_setprio(0);
      }
    asm volatile("s_waitcnt lgkmcnt(0)" ::: "memory");
    __builtin_amdgcn_s_barrier();      // all waves done reading buf[cur]
    if (t + 2 < NT) stage(t + 2, cur);
  }

  if (EPI == 2) {
    float* o = (float*)outp;
#pragma unroll
    for (int mi8 = 0; mi8 < 8; ++mi8)
#pragma unroll
      for (int r = 0; r < 4; ++r) {
        int row = m0 + wr * 128 + mi8 * 16 + lhi * 4 + r;
#pragma unroll
        for (int nj = 0; nj < 4; ++nj) {
          int col = n0 + wc * 64 + nj * 16 + l16;
          o[(size_t)row * N + col] = acc[mi8][nj][r];
        }
      }
  } else {
    u16* o = (u16*)outp;
    const int nheads = N >> 7;
#pragma unroll
    for (int mi8 = 0; mi8 < 8; ++mi8)
#pragma unroll
      for (int r = 0; r < 4; ++r) {
        int row = m0 + wr * 128 + mi8 * 16 + lhi * 4 + r;
        int b = row >> 11;
        int tt = row & 2047;
#pragma unroll
        for (int nj = 0; nj < 4; ++nj) {
          int col = n0 + wc * 64 + nj * 16 + l16;
          int hh = col >> 7, dd = col & 127;
          float v = acc[mi8][nj][r];
          float p = __shfl_xor(v, 1);
          float c = cosp[tt * 64 + (dd >> 1)];
          float s = sinp[tt * 64 + (dd >> 1)];
          v = (lane & 1) ? fmaf(p, s, v * c) : fmaf(v, c, -p * s);
          v *= scale;
          o[((size_t)(b * nheads + hh) * 2048 + tt) * 128 + dd] = f2bf(v);
        }
      }
  }
}

// ---------------- 128x128 2-phase GEMM (KV projection only) ----------------
// EPI 3: merged KV: blocks 0-3 = K heads (RoPE, (b,h,t,d)); blocks 4-7 = V heads,
//        written TRANSPOSED to vtp as (b, kvh, d, t).
template <int EPI>
__global__ __launch_bounds__(256) void gemm_bt(const u16* __restrict__ A,
                                               const u16* __restrict__ B,
                                               void* __restrict__ outp,
                                               u16* __restrict__ vtp,
                                               int M, int N, int K,
                                               const float* __restrict__ cosp,
                                               const float* __restrict__ sinp,
                                               float scale) {
  __shared__ u16 As[128 * 64];
  __shared__ u16 Bs[128 * 64];
  const int tid = threadIdx.x;
  const int lane = tid & 63;
  const int l16 = lane & 15, lhi = lane >> 4;
  const int w = tid >> 6;
  const int wr = w >> 1, wc = w & 1;
  const int m0 = blockIdx.y * 128;
  const int n0 = blockIdx.x * 128;
  const int wbase = tid - lane;

  f32x4 acc[4][4];
#pragma unroll
  for (int i = 0; i < 4; ++i)
#pragma unroll
    for (int j = 0; j < 4; ++j) acc[i][j] = (f32x4)0.0f;

  for (int k0 = 0; k0 < K; k0 += 64) {
    __syncthreads();
#pragma unroll
    for (int j = 0; j < 4; ++j) {
      int c = tid + j * 256;
      gload_lds16(A + (size_t)(m0 + (c >> 3)) * K + k0 + (c & 7) * 8,
                  As + (size_t)(wbase + j * 256) * 8);
    }
#pragma unroll
    for (int j = 0; j < 4; ++j) {
      int c = tid + j * 256;
      gload_lds16(B + (size_t)(n0 + (c >> 3)) * K + k0 + (c & 7) * 8,
                  Bs + (size_t)(wbase + j * 256) * 8);
    }
    __syncthreads();
#pragma unroll
    for (int kk = 0; kk < 64; kk += 32) {
      bf16x8 af[4], bfr[4];
#pragma unroll
      for (int mi = 0; mi < 4; ++mi)
        af[mi] = *(const bf16x8*)&As[(wr * 64 + mi * 16 + l16) * 64 + kk + lhi * 8];
#pragma unroll
      for (int ni = 0; ni < 4; ++ni)
        bfr[ni] = *(const bf16x8*)&Bs[(wc * 64 + ni * 16 + l16) * 64 + kk + lhi * 8];
#pragma unroll
      for (int mi = 0; mi < 4; ++mi)
#pragma unroll
        for (int ni = 0; ni < 4; ++ni)
          acc[mi][ni] = __builtin_amdgcn_mfma_f32_16x16x32_bf16(af[mi], bfr[ni], acc[mi][ni], 0, 0, 0);
    }
  }

  {  // EPI == 3 only (merged KV)
    const int bx = blockIdx.x;
    if (bx < 4) {   // K head bx: RoPE (scale=1), (b, h=bx, t, d) layout
      u16* o = (u16*)outp;
#pragma unroll
      for (int mi = 0; mi < 4; ++mi)
#pragma unroll
        for (int r = 0; r < 4; ++r) {
          int row = m0 + wr * 64 + mi * 16 + lhi * 4 + r;
          int b = row >> 11;
          int t = row & 2047;
          size_t base = ((size_t)(b * 4 + bx) * 2048 + t) * 128;
#pragma unroll
          for (int ni = 0; ni < 4; ++ni) {
            int d = wc * 64 + ni * 16 + l16;
            float v = acc[mi][ni][r];
            float p = __shfl_xor(v, 1);
            float c = cosp[t * 64 + (d >> 1)];
            float s = sinp[t * 64 + (d >> 1)];
            v = (lane & 1) ? fmaf(p, s, v * c) : fmaf(v, c, -p * s);
            o[base + d] = f2bf(v);
          }
        }
    } else {        // V head (bx-4): write V^T (b, kvh, d, t)
      const int kvh = bx - 4;
#pragma unroll
      for (int mi = 0; mi < 4; ++mi)
#pragma unroll
        for (int r = 0; r < 4; ++r) {
          int row = m0 + wr * 64 + mi * 16 + lhi * 4 + r;
          int b = row >> 11;
          int t = row & 2047;
          size_t base = ((size_t)(b * 4 + kvh) * 128) * 2048 + t;
#pragma unroll
          for (int ni = 0; ni < 4; ++ni) {
            int d = wc * 64 + ni * 16 + l16;
            vtp[base + (size_t)d * 2048] = f2bf(acc[mi][ni][r]);
          }
        }
    }
  }
}

// Flash attention: Q (B,H,T,D) bf16, K (B,HKV,T,D) bf16, V^T (B,HKV,D,T) bf16
//   -> O (B,T,H*D) bf16.  (unchanged from round 6)
__global__ __launch_bounds__(512, 4) void attn_kernel(const u16* __restrict__ Q,
                                                      const u16* __restrict__ Kp,
                                                      const u16* __restrict__ Vtp,
                                                      u16* __restrict__ O) {
  __shared__ u16 lds[25600];          // 50KB total
  u16* Ks  = lds;                     // [64][128] swizzled          (8192)
  u16* VTs = lds + 8192;              // [128][64] swizzled V^T      (8192)
  u16* Pb  = lds + 16384;             // 8 x [16][72] per-wave P     (9216)

  const int tid = threadIdx.x;
  const int lane = tid & 63;
  const int w = tid >> 6;
  const int l16 = lane & 15, lhi = lane >> 4;
  const int bid = blockIdx.x;
  const int qt = 15 - (bid >> 6);      // heavy q-tiles dispatched first (LPT)
  const int hb = bid & 63;
  const int h = hb >> 2;
  const int b = hb & 3;
  const int kvh = h >> 2;
  const int q0 = qt * 128;
  const int wbase = tid - lane;
  const int wrow0 = q0 + w * 16;       // this wave's first q row

  const u16* Qb = Q + ((size_t)((b * 16 + h) * 2048 + wrow0)) * 128;
  const u16* Kb = Kp + (size_t)(b * 4 + kvh) * 2048 * 128;
  const u16* Vtb = Vtp + (size_t)(b * 4 + kvh) * 128 * 2048;

  u16* PP = Pb + w * 1152;  // per-wave P [16][72]

  bf16x8 qf[4];
#pragma unroll
  for (int ks = 0; ks < 4; ++ks)
    qf[ks] = *(const bf16x8*)(Qb + (size_t)l16 * 128 + ks * 32 + lhi * 8);

  f32x4 oacc[8];
#pragma unroll
  for (int i = 0; i < 8; ++i) oacc[i] = (f32x4)0.0f;
  float mrow[4], lrow[4];
#pragma unroll
  for (int r = 0; r < 4; ++r) { mrow[r] = -3.0e38f; lrow[r] = 0.0f; }

  const int nkt = 2 * qt + 2;
  for (int kt = 0; kt < nkt; ++kt) {
    const int t0 = kt * 64;
    __syncthreads();
#pragma unroll
    for (int j = 0; j < 2; ++j) {
      int c = tid + j * 512;
      int row = c >> 4;
      int sboff = ((c & 15) * 16) ^ ((row & 7) << 4);   // byte offset within row
      gload_lds16(Kb + (size_t)(t0 + row) * 128 + (sboff >> 1),
                  Ks + (size_t)(wbase + j * 512) * 8);
    }
#pragma unroll
    for (int j = 0; j < 2; ++j) {
      int c = tid + j * 512;
      int d = c >> 3;
      int sboff = ((c & 7) * 16) ^ ((d & 7) << 4);      // byte offset within row (128B)
      gload_lds16(Vtb + (size_t)d * 2048 + t0 + (sboff >> 1),
                  VTs + (size_t)(wbase + j * 512) * 8);
    }
    __syncthreads();

    if (t0 <= wrow0 + 15) {   // wave-uniform: tile has at least one unmasked column
      f32x4 sacc[4];
#pragma unroll
      for (int ni = 0; ni < 4; ++ni) sacc[ni] = (f32x4)0.0f;
      const char* ksb = (const char*)Ks;
#pragma unroll
      for (int ks = 0; ks < 4; ++ks)
#pragma unroll
        for (int ni = 0; ni < 4; ++ni) {
          int row = ni * 16 + l16;
          int boff = row * 256 + ((ks * 64 + lhi * 16) ^ ((l16 & 7) << 4));
          bf16x8 kf = *(const bf16x8*)(ksb + boff);
          sacc[ni] = __builtin_amdgcn_mfma_f32_16x16x32_bf16(qf[ks], kf, sacc[ni], 0, 0, 0);
        }

      if (t0 + 63 > wrow0) {  // tile straddles the diagonal: elementwise causal mask
#pragma unroll
        for (int ni = 0; ni < 4; ++ni)
#pragma unroll
          for (int r = 0; r < 4; ++r) {
            int qrow = wrow0 + lhi * 4 + r;
            int kcol = t0 + ni * 16 + l16;
            if (kcol > qrow) sacc[ni][r] = -3.0e38f;
          }
      }

      float mnew[4];
      bool defer = true;
#pragma unroll
      for (int r = 0; r < 4; ++r) {
        float rm = fmaxf(fmaxf(sacc[0][r], sacc[1][r]), fmaxf(sacc[2][r], sacc[3][r]));
        rm = fmaxf(rm, __shfl_xor(rm, 1));
        rm = fmaxf(rm, __shfl_xor(rm, 2));
        rm = fmaxf(rm, __shfl_xor(rm, 4));
        rm = fmaxf(rm, __shfl_xor(rm, 8));
        mnew[r] = fmaxf(mrow[r], rm);
        defer = defer && (rm <= mrow[r] + 8.0f);
      }
      defer = __all(defer);
      if (defer) {
#pragma unroll
        for (int r = 0; r < 4; ++r) mnew[r] = mrow[r];
      } else {
#pragma unroll
        for (int r = 0; r < 4; ++r) {
          float sc = exp2f(mrow[r] - mnew[r]);
          mrow[r] = mnew[r];
          lrow[r] *= sc;
#pragma unroll
          for (int i = 0; i < 8; ++i) oacc[i][r] *= sc;
        }
      }
      float rs[4] = {0.f, 0.f, 0.f, 0.f};
#pragma unroll
      for (int ni = 0; ni < 4; ++ni)
#pragma unroll
        for (int r = 0; r < 4; ++r) {
          float p = exp2f(sacc[ni][r] - mnew[r]);
          rs[r] += p;
          PP[(lhi * 4 + r) * 72 + ni * 16 + l16] = f2bf(p);
        }
#pragma unroll
      for (int r = 0; r < 4; ++r) {
        float s2 = rs[r];
        s2 += __shfl_xor(s2, 1);
        s2 += __shfl_xor(s2, 2);
        s2 += __shfl_xor(s2, 4);
        s2 += __shfl_xor(s2, 8);
        lrow[r] += s2;
      }

      const char* vtb = (const char*)VTs;
#pragma unroll
      for (int ks = 0; ks < 2; ++ks) {
        bf16x8 pa = *(const bf16x8*)&PP[l16 * 72 + ks * 32 + lhi * 8];
#pragma unroll
        for (int nf = 0; nf < 8; ++nf) {
          int row = nf * 16 + l16;
          int boff = row * 128 + ((ks * 64 + lhi * 16) ^ ((l16 & 7) << 4));
          bf16x8 vb = *(const bf16x8*)(vtb + boff);
          oacc[nf] = __builtin_amdgcn_mfma_f32_16x16x32_bf16(pa, vb, oacc[nf], 0, 0, 0);
        }
      }
    }
  }

  float inv[4];
#pragma unroll
  for (int r = 0; r < 4; ++r) inv[r] = 1.0f / lrow[r];
  __syncthreads();
  u16* OS = lds + w * 2048;
#pragma unroll
  for (int nf = 0; nf < 8; ++nf)
#pragma unroll
    for (int r = 0; r < 4; ++r)
      OS[(lhi * 4 + r) * 128 + nf * 16 + l16] = f2bf(oacc[nf][r] * inv[r]);
  __syncthreads();
  u16* Ob = O + ((size_t)(b * 2048 + wrow0)) * 2048 + h * 128;
#pragma unroll
  for (int j = 0; j < 4; ++j) {
    int c = lane + j * 64;
    int row = c >> 4, dc = (c & 15) * 8;
    *(bf16x8*)(Ob + (size_t)row * 2048 + dc) = *(const bf16x8*)&OS[row * 128 + dc];
  }
}

extern "C" void kernel_launch(void* const* d_in, const int* in_sizes, int n_in,
                              void* d_out, int out_size, void* d_ws, size_t ws_size,
                              hipStream_t stream) {
  (void)in_sizes; (void)n_in; (void)out_size; (void)ws_size;
  const float* x    = (const float*)d_in[0];
  const float* Wq   = (const float*)d_in[1];
  const float* Wk   = (const float*)d_in[2];
  const float* Wv   = (const float*)d_in[3];
  const float* Wo   = (const float*)d_in[4];
  const float* cosp = (const float*)d_in[5];
  const float* sinp = (const float*)d_in[6];

  u16* ws  = (u16*)d_ws;
  u16* xbf = ws;               // 16,777,216 elems (B*T x C)  -- reused as attn out
  u16* Wqb = xbf + 16777216;   //  4,194,304
  u16* Wkb = Wqb + 4194304;    //  1,048,576  } contiguous 1024x2048 KV weight
  u16* Wvb = Wkb + 1048576;    //  1,048,576  }
  u16* Wob = Wvb + 1048576;    //  4,194,304
  u16* Qb  = Wob + 4194304;    // 16,777,216 (B,H,T,D)
  u16* Kb  = Qb + 16777216;    //  4,194,304 (B,HKV,T,D)
  u16* Vb  = Kb + 4194304;     //  4,194,304 (B,HKV,D,T)  == V^T
  u16* AO  = xbf;              // attention output (B,T,C), reuses x region

  cast_bf16_kernel<<<2048, 256, 0, stream>>>(x,  xbf, 16777216L);
  cast_bf16_kernel<<<512,  256, 0, stream>>>(Wq, Wqb, 4194304L);
  cast_bf16_kernel<<<256,  256, 0, stream>>>(Wk, Wkb, 1048576L);
  cast_bf16_kernel<<<256,  256, 0, stream>>>(Wv, Wvb, 1048576L);
  cast_bf16_kernel<<<512,  256, 0, stream>>>(Wo, Wob, 4194304L);

  const float qscale = (float)(1.4426950408889634 / sqrt(128.0));

  gemm_bt256<0><<<dim3(8, 32), 512, 0, stream>>>(xbf, Wqb, Qb, 8192, 2048, 2048, cosp, sinp, qscale);
  gemm_bt<3><<<dim3(8, 64), 256, 0, stream>>>(xbf, Wkb, Kb, Vb, 8192, 1024, 2048, cosp, sinp, 1.0f);

  attn_kernel<<<1024, 512, 0, stream>>>(Qb, Kb, Vb, AO);

  gemm_bt256<2><<<dim3(8, 32), 512, 0, stream>>>(AO, Wob, d_out, 8192, 2048, 2048, nullptr, nullptr, 1.0f);
}

// Round 9
// 338.664 us; speedup vs baseline: 3.0957x; 1.1546x over previous
//
#include <hip/hip_runtime.h>
#include <cmath>

typedef __attribute__((ext_vector_type(8))) short bf16x8;
typedef __attribute__((ext_vector_type(4))) float f32x4;
typedef __attribute__((ext_vector_type(16))) float f32x16;
typedef unsigned short u16;

__device__ __forceinline__ u16 f2bf(float f) {
  union { float f; unsigned u; } x; x.f = f;
  return (u16)((x.u + 0x7FFFu + ((x.u >> 16) & 1u)) >> 16);
}

__device__ __forceinline__ unsigned cvtpk(float lo, float hi) {
  unsigned r;
  asm("v_cvt_pk_bf16_f32 %0, %1, %2" : "=v"(r) : "v"(lo), "v"(hi));
  return r;
}

__device__ __forceinline__ void gload_lds16(const void* g, void* l) {
  __builtin_amdgcn_global_load_lds((const __attribute__((address_space(1))) unsigned*)g,
                                   (__attribute__((address_space(3))) unsigned*)l,
                                   16, 0, 0);
}

__global__ __launch_bounds__(256) void cast_bf16_kernel(const float* __restrict__ in,
                                                        u16* __restrict__ out, long n) {
  long i = (long)blockIdx.x * blockDim.x + threadIdx.x;
  long stride = (long)gridDim.x * blockDim.x;
  for (long j = i * 4; j < n; j += stride * 4) {
    float4 v = *(const float4*)(in + j);
    ushort4 o;
    o.x = f2bf(v.x); o.y = f2bf(v.y); o.z = f2bf(v.z); o.w = f2bf(v.w);
    *(ushort4*)(out + j) = o;
  }
}

// ---------------- 256x256 counted-vmcnt deep-pipeline GEMM (unchanged) ----------------
template <int EPI>
__global__ __launch_bounds__(512, 2) void gemm_bt256(const u16* __restrict__ A,
                                                     const u16* __restrict__ B,
                                                     void* __restrict__ outp,
                                                     int M, int N, int K,
                                                     const float* __restrict__ cosp,
                                                     const float* __restrict__ sinp,
                                                     float scale) {
  __shared__ u16 lds[65536];   // [buf][A 256x64 | B 256x64], 128KB
  const int tid = threadIdx.x;
  const int lane = tid & 63;
  const int l16 = lane & 15, lhi = lane >> 4;
  const int w = tid >> 6;
  const int wr = w >> 2, wc = w & 3;
  const int m0 = blockIdx.y * 256;
  const int n0 = blockIdx.x * 256;

  f32x4 acc[8][4];
#pragma unroll
  for (int i = 0; i < 8; ++i)
#pragma unroll
    for (int j = 0; j < 4; ++j) acc[i][j] = (f32x4)0.0f;

  const int NT = K >> 6;

  auto stage = [&](int t, int buf) {
    const int k0 = t << 6;
    u16* Ad = lds + buf * 32768;
    u16* Bd = Ad + 16384;
#pragma unroll
    for (int j = 0; j < 4; ++j) {
      int c = tid + j * 512;
      int row = c >> 3;
      int sboff = ((c & 7) * 16) ^ ((row & 7) << 4);
      gload_lds16(A + (size_t)(m0 + row) * K + k0 + (sboff >> 1), Ad + (size_t)c * 8);
    }
#pragma unroll
    for (int j = 0; j < 4; ++j) {
      int c = tid + j * 512;
      int row = c >> 3;
      int sboff = ((c & 7) * 16) ^ ((row & 7) << 4);
      gload_lds16(B + (size_t)(n0 + row) * K + k0 + (sboff >> 1), Bd + (size_t)c * 8);
    }
  };

  stage(0, 0);
  stage(1, 1);

  for (int t = 0; t < NT; ++t) {
    const int cur = t & 1;
    if (t + 1 < NT) { asm volatile("s_waitcnt vmcnt(8)" ::: "memory"); }
    else            { asm volatile("s_waitcnt vmcnt(0)" ::: "memory"); }
    __builtin_amdgcn_s_barrier();
    const char* Ab = (const char*)(lds + cur * 32768);
    const char* Bb = (const char*)(lds + cur * 32768 + 16384);
#pragma unroll
    for (int qm = 0; qm < 2; ++qm)
#pragma unroll
      for (int qn = 0; qn < 2; ++qn) {
        bf16x8 af[4][2], bfr[2][2];
#pragma unroll
        for (int mi = 0; mi < 4; ++mi) {
          int ra = wr * 128 + qm * 64 + mi * 16 + l16;
#pragma unroll
          for (int kk = 0; kk < 2; ++kk)
            af[mi][kk] = *(const bf16x8*)(Ab + ra * 128 + ((kk * 64 + lhi * 16) ^ ((ra & 7) << 4)));
        }
#pragma unroll
        for (int ni = 0; ni < 2; ++ni) {
          int rb = wc * 64 + qn * 32 + ni * 16 + l16;
#pragma unroll
          for (int kk = 0; kk < 2; ++kk)
            bfr[ni][kk] = *(const bf16x8*)(Bb + rb * 128 + ((kk * 64 + lhi * 16) ^ ((rb & 7) << 4)));
        }
        __builtin_amdgcn_s_setprio(1);
#pragma unroll
        for (int kk = 0; kk < 2; ++kk)
#pragma unroll
          for (int mi = 0; mi < 4; ++mi)
#pragma unroll
            for (int ni = 0; ni < 2; ++ni)
              acc[qm * 4 + mi][qn * 2 + ni] = __builtin_amdgcn_mfma_f32_16x16x32_bf16(
                  af[mi][kk], bfr[ni][kk], acc[qm * 4 + mi][qn * 2 + ni], 0, 0, 0);
        __builtin_amdgcn_s_setprio(0);
      }
    asm volatile("s_waitcnt lgkmcnt(0)" ::: "memory");
    __builtin_amdgcn_s_barrier();
    if (t + 2 < NT) stage(t + 2, cur);
  }

  if (EPI == 2) {
    float* o = (float*)outp;
#pragma unroll
    for (int mi8 = 0; mi8 < 8; ++mi8)
#pragma unroll
      for (int r = 0; r < 4; ++r) {
        int row = m0 + wr * 128 + mi8 * 16 + lhi * 4 + r;
#pragma unroll
        for (int nj = 0; nj < 4; ++nj) {
          int col = n0 + wc * 64 + nj * 16 + l16;
          o[(size_t)row * N + col] = acc[mi8][nj][r];
        }
      }
  } else {
    u16* o = (u16*)outp;
    const int nheads = N >> 7;
#pragma unroll
    for (int mi8 = 0; mi8 < 8; ++mi8)
#pragma unroll
      for (int r = 0; r < 4; ++r) {
        int row = m0 + wr * 128 + mi8 * 16 + lhi * 4 + r;
        int b = row >> 11;
        int tt = row & 2047;
#pragma unroll
        for (int nj = 0; nj < 4; ++nj) {
          int col = n0 + wc * 64 + nj * 16 + l16;
          int hh = col >> 7, dd = col & 127;
          float v = acc[mi8][nj][r];
          float p = __shfl_xor(v, 1);
          float c = cosp[tt * 64 + (dd >> 1)];
          float s = sinp[tt * 64 + (dd >> 1)];
          v = (lane & 1) ? fmaf(p, s, v * c) : fmaf(v, c, -p * s);
          v *= scale;
          o[((size_t)(b * nheads + hh) * 2048 + tt) * 128 + dd] = f2bf(v);
        }
      }
  }
}

// ---------------- 128x128 2-phase GEMM (KV projection only, unchanged) ----------------
template <int EPI>
__global__ __launch_bounds__(256) void gemm_bt(const u16* __restrict__ A,
                                               const u16* __restrict__ B,
                                               void* __restrict__ outp,
                                               u16* __restrict__ vtp,
                                               int M, int N, int K,
                                               const float* __restrict__ cosp,
                                               const float* __restrict__ sinp,
                                               float scale) {
  __shared__ u16 As[128 * 64];
  __shared__ u16 Bs[128 * 64];
  const int tid = threadIdx.x;
  const int lane = tid & 63;
  const int l16 = lane & 15, lhi = lane >> 4;
  const int w = tid >> 6;
  const int wr = w >> 1, wc = w & 1;
  const int m0 = blockIdx.y * 128;
  const int n0 = blockIdx.x * 128;
  const int wbase = tid - lane;

  f32x4 acc[4][4];
#pragma unroll
  for (int i = 0; i < 4; ++i)
#pragma unroll
    for (int j = 0; j < 4; ++j) acc[i][j] = (f32x4)0.0f;

  for (int k0 = 0; k0 < K; k0 += 64) {
    __syncthreads();
#pragma unroll
    for (int j = 0; j < 4; ++j) {
      int c = tid + j * 256;
      gload_lds16(A + (size_t)(m0 + (c >> 3)) * K + k0 + (c & 7) * 8,
                  As + (size_t)(wbase + j * 256) * 8);
    }
#pragma unroll
    for (int j = 0; j < 4; ++j) {
      int c = tid + j * 256;
      gload_lds16(B + (size_t)(n0 + (c >> 3)) * K + k0 + (c & 7) * 8,
                  Bs + (size_t)(wbase + j * 256) * 8);
    }
    __syncthreads();
#pragma unroll
    for (int kk = 0; kk < 64; kk += 32) {
      bf16x8 af[4], bfr[4];
#pragma unroll
      for (int mi = 0; mi < 4; ++mi)
        af[mi] = *(const bf16x8*)&As[(wr * 64 + mi * 16 + l16) * 64 + kk + lhi * 8];
#pragma unroll
      for (int ni = 0; ni < 4; ++ni)
        bfr[ni] = *(const bf16x8*)&Bs[(wc * 64 + ni * 16 + l16) * 64 + kk + lhi * 8];
#pragma unroll
      for (int mi = 0; mi < 4; ++mi)
#pragma unroll
        for (int ni = 0; ni < 4; ++ni)
          acc[mi][ni] = __builtin_amdgcn_mfma_f32_16x16x32_bf16(af[mi], bfr[ni], acc[mi][ni], 0, 0, 0);
    }
  }

  {  // EPI == 3 (merged KV)
    const int bx = blockIdx.x;
    if (bx < 4) {
      u16* o = (u16*)outp;
#pragma unroll
      for (int mi = 0; mi < 4; ++mi)
#pragma unroll
        for (int r = 0; r < 4; ++r) {
          int row = m0 + wr * 64 + mi * 16 + lhi * 4 + r;
          int b = row >> 11;
          int t = row & 2047;
          size_t base = ((size_t)(b * 4 + bx) * 2048 + t) * 128;
#pragma unroll
          for (int ni = 0; ni < 4; ++ni) {
            int d = wc * 64 + ni * 16 + l16;
            float v = acc[mi][ni][r];
            float p = __shfl_xor(v, 1);
            float c = cosp[t * 64 + (d >> 1)];
            float s = sinp[t * 64 + (d >> 1)];
            v = (lane & 1) ? fmaf(p, s, v * c) : fmaf(v, c, -p * s);
            o[base + d] = f2bf(v);
          }
        }
    } else {
      const int kvh = bx - 4;
#pragma unroll
      for (int mi = 0; mi < 4; ++mi)
#pragma unroll
        for (int r = 0; r < 4; ++r) {
          int row = m0 + wr * 64 + mi * 16 + lhi * 4 + r;
          int b = row >> 11;
          int t = row & 2047;
          size_t base = ((size_t)(b * 4 + kvh) * 128) * 2048 + t;
#pragma unroll
          for (int ni = 0; ni < 4; ++ni) {
            int d = wc * 64 + ni * 16 + l16;
            vtp[base + (size_t)d * 2048] = f2bf(acc[mi][ni][r]);
          }
        }
    }
  }
}

// ---------------- Flash attention, 32x32 swapped-QK^T structure ----------------
// Q (B,H,T,D) bf16 (pre-scaled), K (B,HKV,T,D) bf16, V^T (B,HKV,D,T) bf16 -> O (B,T,H*D) bf16.
// Block = (b, h, 128-row q tile); 4 waves x 32 q-rows; KV tile 64.
// QK^T: S^T = mfma_32x32x16(A=K, B=Q) -> lane holds q = lane&31 (col), kv in regs -> softmax in-lane.
// PV:   O^T = mfma_32x32x16(A=V^T, B=P) -> lane holds q col, d rows in regs -> rescale in-lane.
// Verified C/D layout (m74/m101): col=lane&31, row=(reg&3)+8*(reg>>2)+4*(lane>>5).
// A/B layouts by symmetry with the verified 16x16 usage: row/col=lane&31, k=(lane>>5)*8+e.
// P redistribution for B-frag: cvt_pk pairs + shfl_xor(32) + per-hi select (derivation in comments).
// FIX vs round 8: K/V LDS staging destinations are the wave-uniform linear form
//   Ks/VTs + (wbase + j*256)*8  (element = c*8). Round 8's (j>>1)*8192 term wrote K rows
//   32-63 into the VTs region (element offset, not bytes) -> corrupted both tiles.
__global__ __launch_bounds__(256, 2) void attn_kernel(const u16* __restrict__ Q,
                                                      const u16* __restrict__ Kp,
                                                      const u16* __restrict__ Vtp,
                                                      u16* __restrict__ O) {
  __shared__ u16 lds[17408];          // 34.8KB: Ks 8192 | VTs 8192; OS overlay 4x32x136
  u16* Ks  = lds;                     // [64][128] swizzled (key row&15)
  u16* VTs = lds + 8192;              // [128][64] swizzled V^T (key row&7)

  const int tid = threadIdx.x;
  const int lane = tid & 63;
  const int w = tid >> 6;
  const int l5 = lane & 31, hi = lane >> 5;
  const int bid = blockIdx.x;
  const int qt = 15 - (bid >> 6);      // LPT: heavy q-tiles first
  const int hb = bid & 63;
  const int h = hb >> 2;
  const int b = hb & 3;
  const int kvh = h >> 2;
  const int q0 = qt * 128;
  const int wbase = tid - lane;
  const int wrow0 = q0 + w * 32;       // this wave's first q row
  const int qg = wrow0 + l5;           // this lane's q row (col of all MFMAs)

  const u16* Qb = Q + ((size_t)((b * 16 + h) * 2048 + wrow0)) * 128;
  const u16* Kb = Kp + (size_t)(b * 4 + kvh) * 2048 * 128;
  const u16* Vtb = Vtp + (size_t)(b * 4 + kvh) * 128 * 2048;

  // Q B-frags: qf[ks] = Q[q=l5][d = ks*16 + hi*8 + 0..7]
  bf16x8 qf[8];
#pragma unroll
  for (int ks = 0; ks < 8; ++ks)
    qf[ks] = *(const bf16x8*)(Qb + (size_t)l5 * 128 + ks * 16 + hi * 8);

  f32x16 oacc[4];   // O^T: D[row=d_local][col=q], per 32-d tile
#pragma unroll
  for (int i = 0; i < 4; ++i) oacc[i] = (f32x16)0.0f;
  float m = -3.0e38f, l = 0.0f;

  const int nkt = 2 * qt + 2;
  for (int kt = 0; kt < nkt; ++kt) {
    const int t0 = kt * 64;
    __syncthreads();
    // stage K tile [64][128]: LDS element c*8 (wave-uniform base), source pre-swizzled
#pragma unroll
    for (int j = 0; j < 4; ++j) {
      int c = tid + j * 256;
      int row = c >> 4;
      int sboff = ((c & 15) * 16) ^ ((row & 15) << 4);
      gload_lds16(Kb + (size_t)(t0 + row) * 128 + (sboff >> 1),
                  Ks + (size_t)(wbase + j * 256) * 8);
    }
    // stage V^T tile [128][64]: LDS element c*8 (wave-uniform base), source pre-swizzled
#pragma unroll
    for (int j = 0; j < 4; ++j) {
      int c = tid + j * 256;
      int d = c >> 3;
      int sboff = ((c & 7) * 16) ^ ((d & 7) << 4);
      gload_lds16(Vtb + (size_t)d * 2048 + t0 + (sboff >> 1),
                  VTs + (size_t)(wbase + j * 256) * 8);
    }
    __syncthreads();

    if (t0 <= wrow0 + 31) {   // wave-uniform guard
      // S^T = mfma(K, Q): p[kt2*16+r] = S[kv][q], kv = kt2*32 + (r&3)+8*(r>>2)+4*hi
      float p[32];
      const char* ksb = (const char*)Ks;
#pragma unroll
      for (int kt2 = 0; kt2 < 2; ++kt2) {
        f32x16 sacc = (f32x16)0.0f;
        int row = kt2 * 32 + l5;
#pragma unroll
        for (int ks = 0; ks < 8; ++ks) {
          bf16x8 kf = *(const bf16x8*)(ksb + row * 256 + ((ks * 32 + hi * 16) ^ ((row & 15) << 4)));
          sacc = __builtin_amdgcn_mfma_f32_32x32x16_bf16(kf, qf[ks], sacc, 0, 0, 0);
        }
#pragma unroll
        for (int r = 0; r < 16; ++r) p[kt2 * 16 + r] = sacc[r];
      }

      if (t0 + 63 > wrow0) {  // straddles diagonal: causal mask
#pragma unroll
        for (int kt2 = 0; kt2 < 2; ++kt2)
#pragma unroll
          for (int r = 0; r < 16; ++r) {
            int kvg = t0 + kt2 * 32 + (r & 3) + 8 * (r >> 2) + 4 * hi;
            if (kvg > qg) p[kt2 * 16 + r] = -3.0e38f;
          }
      }

      // in-lane row max (tree) + cross-half combine
      float mx[16];
#pragma unroll
      for (int i = 0; i < 16; ++i) mx[i] = fmaxf(p[i], p[i + 16]);
#pragma unroll
      for (int i = 0; i < 8; ++i) mx[i] = fmaxf(mx[i], mx[i + 8]);
#pragma unroll
      for (int i = 0; i < 4; ++i) mx[i] = fmaxf(mx[i], mx[i + 4]);
      float rm = fmaxf(fmaxf(mx[0], mx[1]), fmaxf(mx[2], mx[3]));
      rm = fmaxf(rm, __shfl_xor(rm, 32));

      bool defer = __all(rm <= m + 8.0f);
      if (!defer) {
        float mnew = fmaxf(m, rm);
        float sc = exp2f(m - mnew);
        m = mnew;
        l *= sc;
#pragma unroll
        for (int i = 0; i < 4; ++i)
#pragma unroll
          for (int r = 0; r < 16; ++r) oacc[i][r] *= sc;
      }

      // p = exp2(S - m); in-lane sum
#pragma unroll
      for (int i = 0; i < 32; ++i) p[i] = exp2f(p[i] - m);
      float sm[16];
#pragma unroll
      for (int i = 0; i < 16; ++i) sm[i] = p[i] + p[i + 16];
#pragma unroll
      for (int i = 0; i < 8; ++i) sm[i] += sm[i + 8];
#pragma unroll
      for (int i = 0; i < 4; ++i) sm[i] += sm[i + 4];
      float s2 = (sm[0] + sm[1]) + (sm[2] + sm[3]);
      s2 += __shfl_xor(s2, 32);
      l += s2;

      // P pack + redistribute + PV:  O^T += mfma(A=V^T, B=P)
      // held: p[kt2*16+r] has kv_local=(r&3)+8*(r>>2)+4*hi; B-frag k-step s needs kv=s*16+hi*8+e.
      // hi=0 needs kv(0..7)  = {own (0,1),(2,3) | other-half (4,5),(6,7)} = {A0,A1,XA0,XA1}
      // hi=1 needs kv(8..15) = {other-half (8,9),(10,11) | own (12,13),(14,15)} = {XA2,XA3,A2,A3}
      const char* vtb = (const char*)VTs;
#pragma unroll
      for (int kt2 = 0; kt2 < 2; ++kt2) {
#pragma unroll
        for (int sl = 0; sl < 2; ++sl) {   // kv 16-step within the 32-tile
          int base = kt2 * 16 + sl * 8;
          unsigned A0 = cvtpk(p[base + 0], p[base + 1]);
          unsigned A1 = cvtpk(p[base + 2], p[base + 3]);
          unsigned A2 = cvtpk(p[base + 4], p[base + 5]);
          unsigned A3 = cvtpk(p[base + 6], p[base + 7]);
          unsigned XA0 = __shfl_xor(A0, 32);
          unsigned XA1 = __shfl_xor(A1, 32);
          unsigned XA2 = __shfl_xor(A2, 32);
          unsigned XA3 = __shfl_xor(A3, 32);
          union { unsigned u[4]; bf16x8 v; } pf;
          pf.u[0] = hi ? XA2 : A0;
          pf.u[1] = hi ? XA3 : A1;
          pf.u[2] = hi ? A2 : XA0;
          pf.u[3] = hi ? A3 : XA1;
          int s = kt2 * 2 + sl;
#pragma unroll
          for (int dt = 0; dt < 4; ++dt) {
            int row = dt * 32 + l5;
            bf16x8 vb = *(const bf16x8*)(vtb + row * 128 + ((s * 32 + hi * 16) ^ ((row & 7) << 4)));
            oacc[dt] = __builtin_amdgcn_mfma_f32_32x32x16_bf16(vb, pf.v, oacc[dt], 0, 0, 0);
          }
        }
      }
    }
  }

  // normalize (in-lane: l is this lane's own q row), stage via padded LDS, coalesced store
  float inv = 1.0f / l;
  __syncthreads();
  u16* OS = lds + w * 4352;            // [32 q][136] padded
#pragma unroll
  for (int dt = 0; dt < 4; ++dt)
#pragma unroll
    for (int r = 0; r < 16; ++r) {
      int d = dt * 32 + (r & 3) + 8 * (r >> 2) + 4 * hi;
      OS[l5 * 136 + d] = f2bf(oacc[dt][r] * inv);
    }
  __syncthreads();
  u16* Ob = O + ((size_t)(b * 2048 + q0)) * 2048 + h * 128;
#pragma unroll
  for (int j = 0; j < 8; ++j) {
    int c = tid + j * 256;
    int row = c >> 4, col = c & 15;
    *(bf16x8*)(Ob + (size_t)row * 2048 + col * 8) =
        *(const bf16x8*)&lds[(row >> 5) * 4352 + (row & 31) * 136 + col * 8];
  }
}

extern "C" void kernel_launch(void* const* d_in, const int* in_sizes, int n_in,
                              void* d_out, int out_size, void* d_ws, size_t ws_size,
                              hipStream_t stream) {
  (void)in_sizes; (void)n_in; (void)out_size; (void)ws_size;
  const float* x    = (const float*)d_in[0];
  const float* Wq   = (const float*)d_in[1];
  const float* Wk   = (const float*)d_in[2];
  const float* Wv   = (const float*)d_in[3];
  const float* Wo   = (const float*)d_in[4];
  const float* cosp = (const float*)d_in[5];
  const float* sinp = (const float*)d_in[6];

  u16* ws  = (u16*)d_ws;
  u16* xbf = ws;               // 16,777,216 elems (B*T x C)  -- reused as attn out
  u16* Wqb = xbf + 16777216;   //  4,194,304
  u16* Wkb = Wqb + 4194304;    //  1,048,576  } contiguous 1024x2048 KV weight
  u16* Wvb = Wkb + 1048576;    //  1,048,576  }
  u16* Wob = Wvb + 1048576;    //  4,194,304
  u16* Qb  = Wob + 4194304;    // 16,777,216 (B,H,T,D)
  u16* Kb  = Qb + 16777216;    //  4,194,304 (B,HKV,T,D)
  u16* Vb  = Kb + 4194304;     //  4,194,304 (B,HKV,D,T)  == V^T
  u16* AO  = xbf;              // attention output (B,T,C), reuses x region

  cast_bf16_kernel<<<2048, 256, 0, stream>>>(x,  xbf, 16777216L);
  cast_bf16_kernel<<<512,  256, 0, stream>>>(Wq, Wqb, 4194304L);
  cast_bf16_kernel<<<256,  256, 0, stream>>>(Wk, Wkb, 1048576L);
  cast_bf16_kernel<<<256,  256, 0, stream>>>(Wv, Wvb, 1048576L);
  cast_bf16_kernel<<<512,  256, 0, stream>>>(Wo, Wob, 4194304L);

  const float qscale = (float)(1.4426950408889634 / sqrt(128.0));

  gemm_bt256<0><<<dim3(8, 32), 512, 0, stream>>>(xbf, Wqb, Qb, 8192, 2048, 2048, cosp, sinp, qscale);
  gemm_bt<3><<<dim3(8, 64), 256, 0, stream>>>(xbf, Wkb, Kb, Vb, 8192, 1024, 2048, cosp, sinp, 1.0f);

  attn_kernel<<<1024, 256, 0, stream>>>(Qb, Kb, Vb, AO);

  gemm_bt256<2><<<dim3(8, 32), 512, 0, stream>>>(AO, Wob, d_out, 8192, 2048, 2048, nullptr, nullptr, 1.0f);
}

// Round 10
// 324.510 us; speedup vs baseline: 3.2307x; 1.0436x over previous
//
#include <hip/hip_runtime.h>
#include <cmath>

typedef __attribute__((ext_vector_type(8))) short bf16x8;
typedef __attribute__((ext_vector_type(4))) float f32x4;
typedef __attribute__((ext_vector_type(16))) float f32x16;
typedef unsigned short u16;

__device__ __forceinline__ u16 f2bf(float f) {
  union { float f; unsigned u; } x; x.f = f;
  return (u16)((x.u + 0x7FFFu + ((x.u >> 16) & 1u)) >> 16);
}

__device__ __forceinline__ unsigned cvtpk(float lo, float hi) {
  unsigned r;
  asm("v_cvt_pk_bf16_f32 %0, %1, %2" : "=v"(r) : "v"(lo), "v"(hi));
  return r;
}

__device__ __forceinline__ void gload_lds16(const void* g, void* l) {
  __builtin_amdgcn_global_load_lds((const __attribute__((address_space(1))) unsigned*)g,
                                   (__attribute__((address_space(3))) unsigned*)l,
                                   16, 0, 0);
}

// One fused cast: dst segments are contiguous in ws:
// [x 16777216 | wq 4194304 | wk 1048576 | wv 1048576 | wo 4194304]
__global__ __launch_bounds__(256) void cast_all_kernel(const float* __restrict__ x,
                                                       const float* __restrict__ wq,
                                                       const float* __restrict__ wk,
                                                       const float* __restrict__ wv,
                                                       const float* __restrict__ wo,
                                                       u16* __restrict__ out) {
  const long b1 = 16777216, b2 = 20971520, b3 = 22020096, b4 = 23068672, b5 = 27262976;
  long i = (long)blockIdx.x * blockDim.x + threadIdx.x;
  long stride = (long)gridDim.x * blockDim.x;
  for (long j = i * 4; j < b5; j += stride * 4) {
    const float* src; long off;
    if (j < b1)      { src = x;  off = j; }
    else if (j < b2) { src = wq; off = j - b1; }
    else if (j < b3) { src = wk; off = j - b2; }
    else if (j < b4) { src = wv; off = j - b3; }
    else             { src = wo; off = j - b4; }
    float4 v = *(const float4*)(src + off);
    ushort4 o;
    o.x = f2bf(v.x); o.y = f2bf(v.y); o.z = f2bf(v.z); o.w = f2bf(v.w);
    *(ushort4*)(out + j) = o;
  }
}

// ---------------- 256x256 counted-vmcnt deep-pipeline GEMM (unchanged) ----------------
template <int EPI>
__global__ __launch_bounds__(512, 2) void gemm_bt256(const u16* __restrict__ A,
                                                     const u16* __restrict__ B,
                                                     void* __restrict__ outp,
                                                     int M, int N, int K,
                                                     const float* __restrict__ cosp,
                                                     const float* __restrict__ sinp,
                                                     float scale) {
  __shared__ u16 lds[65536];   // [buf][A 256x64 | B 256x64], 128KB
  const int tid = threadIdx.x;
  const int lane = tid & 63;
  const int l16 = lane & 15, lhi = lane >> 4;
  const int w = tid >> 6;
  const int wr = w >> 2, wc = w & 3;
  const int m0 = blockIdx.y * 256;
  const int n0 = blockIdx.x * 256;

  f32x4 acc[8][4];
#pragma unroll
  for (int i = 0; i < 8; ++i)
#pragma unroll
    for (int j = 0; j < 4; ++j) acc[i][j] = (f32x4)0.0f;

  const int NT = K >> 6;

  auto stage = [&](int t, int buf) {
    const int k0 = t << 6;
    u16* Ad = lds + buf * 32768;
    u16* Bd = Ad + 16384;
#pragma unroll
    for (int j = 0; j < 4; ++j) {
      int c = tid + j * 512;
      int row = c >> 3;
      int sboff = ((c & 7) * 16) ^ ((row & 7) << 4);
      gload_lds16(A + (size_t)(m0 + row) * K + k0 + (sboff >> 1), Ad + (size_t)c * 8);
    }
#pragma unroll
    for (int j = 0; j < 4; ++j) {
      int c = tid + j * 512;
      int row = c >> 3;
      int sboff = ((c & 7) * 16) ^ ((row & 7) << 4);
      gload_lds16(B + (size_t)(n0 + row) * K + k0 + (sboff >> 1), Bd + (size_t)c * 8);
    }
  };

  stage(0, 0);
  stage(1, 1);

  for (int t = 0; t < NT; ++t) {
    const int cur = t & 1;
    if (t + 1 < NT) { asm volatile("s_waitcnt vmcnt(8)" ::: "memory"); }
    else            { asm volatile("s_waitcnt vmcnt(0)" ::: "memory"); }
    __builtin_amdgcn_s_barrier();
    const char* Ab = (const char*)(lds + cur * 32768);
    const char* Bb = (const char*)(lds + cur * 32768 + 16384);
#pragma unroll
    for (int qm = 0; qm < 2; ++qm)
#pragma unroll
      for (int qn = 0; qn < 2; ++qn) {
        bf16x8 af[4][2], bfr[2][2];
#pragma unroll
        for (int mi = 0; mi < 4; ++mi) {
          int ra = wr * 128 + qm * 64 + mi * 16 + l16;
#pragma unroll
          for (int kk = 0; kk < 2; ++kk)
            af[mi][kk] = *(const bf16x8*)(Ab + ra * 128 + ((kk * 64 + lhi * 16) ^ ((ra & 7) << 4)));
        }
#pragma unroll
        for (int ni = 0; ni < 2; ++ni) {
          int rb = wc * 64 + qn * 32 + ni * 16 + l16;
#pragma unroll
          for (int kk = 0; kk < 2; ++kk)
            bfr[ni][kk] = *(const bf16x8*)(Bb + rb * 128 + ((kk * 64 + lhi * 16) ^ ((rb & 7) << 4)));
        }
        __builtin_amdgcn_s_setprio(1);
#pragma unroll
        for (int kk = 0; kk < 2; ++kk)
#pragma unroll
          for (int mi = 0; mi < 4; ++mi)
#pragma unroll
            for (int ni = 0; ni < 2; ++ni)
              acc[qm * 4 + mi][qn * 2 + ni] = __builtin_amdgcn_mfma_f32_16x16x32_bf16(
                  af[mi][kk], bfr[ni][kk], acc[qm * 4 + mi][qn * 2 + ni], 0, 0, 0);
        __builtin_amdgcn_s_setprio(0);
      }
    asm volatile("s_waitcnt lgkmcnt(0)" ::: "memory");
    __builtin_amdgcn_s_barrier();
    if (t + 2 < NT) stage(t + 2, cur);
  }

  if (EPI == 2) {
    float* o = (float*)outp;
#pragma unroll
    for (int mi8 = 0; mi8 < 8; ++mi8)
#pragma unroll
      for (int r = 0; r < 4; ++r) {
        int row = m0 + wr * 128 + mi8 * 16 + lhi * 4 + r;
#pragma unroll
        for (int nj = 0; nj < 4; ++nj) {
          int col = n0 + wc * 64 + nj * 16 + l16;
          o[(size_t)row * N + col] = acc[mi8][nj][r];
        }
      }
  } else {
    u16* o = (u16*)outp;
    const int nheads = N >> 7;
#pragma unroll
    for (int mi8 = 0; mi8 < 8; ++mi8)
#pragma unroll
      for (int r = 0; r < 4; ++r) {
        int row = m0 + wr * 128 + mi8 * 16 + lhi * 4 + r;
        int b = row >> 11;
        int tt = row & 2047;
#pragma unroll
        for (int nj = 0; nj < 4; ++nj) {
          int col = n0 + wc * 64 + nj * 16 + l16;
          int hh = col >> 7, dd = col & 127;
          float v = acc[mi8][nj][r];
          float p = __shfl_xor(v, 1);
          float c = cosp[tt * 64 + (dd >> 1)];
          float s = sinp[tt * 64 + (dd >> 1)];
          v = (lane & 1) ? fmaf(p, s, v * c) : fmaf(v, c, -p * s);
          v *= scale;
          o[((size_t)(b * nheads + hh) * 2048 + tt) * 128 + dd] = f2bf(v);
        }
      }
  }
}

// ---------------- 128x128 2-phase GEMM (KV projection only, unchanged) ----------------
template <int EPI>
__global__ __launch_bounds__(256) void gemm_bt(const u16* __restrict__ A,
                                               const u16* __restrict__ B,
                                               void* __restrict__ outp,
                                               u16* __restrict__ vtp,
                                               int M, int N, int K,
                                               const float* __restrict__ cosp,
                                               const float* __restrict__ sinp,
                                               float scale) {
  __shared__ u16 As[128 * 64];
  __shared__ u16 Bs[128 * 64];
  const int tid = threadIdx.x;
  const int lane = tid & 63;
  const int l16 = lane & 15, lhi = lane >> 4;
  const int w = tid >> 6;
  const int wr = w >> 1, wc = w & 1;
  const int m0 = blockIdx.y * 128;
  const int n0 = blockIdx.x * 128;
  const int wbase = tid - lane;

  f32x4 acc[4][4];
#pragma unroll
  for (int i = 0; i < 4; ++i)
#pragma unroll
    for (int j = 0; j < 4; ++j) acc[i][j] = (f32x4)0.0f;

  for (int k0 = 0; k0 < K; k0 += 64) {
    __syncthreads();
#pragma unroll
    for (int j = 0; j < 4; ++j) {
      int c = tid + j * 256;
      gload_lds16(A + (size_t)(m0 + (c >> 3)) * K + k0 + (c & 7) * 8,
                  As + (size_t)(wbase + j * 256) * 8);
    }
#pragma unroll
    for (int j = 0; j < 4; ++j) {
      int c = tid + j * 256;
      gload_lds16(B + (size_t)(n0 + (c >> 3)) * K + k0 + (c & 7) * 8,
                  Bs + (size_t)(wbase + j * 256) * 8);
    }
    __syncthreads();
#pragma unroll
    for (int kk = 0; kk < 64; kk += 32) {
      bf16x8 af[4], bfr[4];
#pragma unroll
      for (int mi = 0; mi < 4; ++mi)
        af[mi] = *(const bf16x8*)&As[(wr * 64 + mi * 16 + l16) * 64 + kk + lhi * 8];
#pragma unroll
      for (int ni = 0; ni < 4; ++ni)
        bfr[ni] = *(const bf16x8*)&Bs[(wc * 64 + ni * 16 + l16) * 64 + kk + lhi * 8];
#pragma unroll
      for (int mi = 0; mi < 4; ++mi)
#pragma unroll
        for (int ni = 0; ni < 4; ++ni)
          acc[mi][ni] = __builtin_amdgcn_mfma_f32_16x16x32_bf16(af[mi], bfr[ni], acc[mi][ni], 0, 0, 0);
    }
  }

  {  // EPI == 3 (merged KV)
    const int bx = blockIdx.x;
    if (bx < 4) {
      u16* o = (u16*)outp;
#pragma unroll
      for (int mi = 0; mi < 4; ++mi)
#pragma unroll
        for (int r = 0; r < 4; ++r) {
          int row = m0 + wr * 64 + mi * 16 + lhi * 4 + r;
          int b = row >> 11;
          int t = row & 2047;
          size_t base = ((size_t)(b * 4 + bx) * 2048 + t) * 128;
#pragma unroll
          for (int ni = 0; ni < 4; ++ni) {
            int d = wc * 64 + ni * 16 + l16;
            float v = acc[mi][ni][r];
            float p = __shfl_xor(v, 1);
            float c = cosp[t * 64 + (d >> 1)];
            float s = sinp[t * 64 + (d >> 1)];
            v = (lane & 1) ? fmaf(p, s, v * c) : fmaf(v, c, -p * s);
            o[base + d] = f2bf(v);
          }
        }
    } else {
      const int kvh = bx - 4;
#pragma unroll
      for (int mi = 0; mi < 4; ++mi)
#pragma unroll
        for (int r = 0; r < 4; ++r) {
          int row = m0 + wr * 64 + mi * 16 + lhi * 4 + r;
          int b = row >> 11;
          int t = row & 2047;
          size_t base = ((size_t)(b * 4 + kvh) * 128) * 2048 + t;
#pragma unroll
          for (int ni = 0; ni < 4; ++ni) {
            int d = wc * 64 + ni * 16 + l16;
            vtp[base + (size_t)d * 2048] = f2bf(acc[mi][ni][r]);
          }
        }
    }
  }
}

// ---------------- Flash attention: 32x32 swapped-QK^T + K/V double-buffer ----------------
// Block = (b, h, 256-row q tile); 8 waves x 32 q-rows; KV tile 64, double-buffered.
// Pipeline per tile (gemm_bt256-proven pattern): issue stage(kt+1) -> vmcnt(4)
// [tile kt's 4 loads landed, kt+1's in flight] -> s_barrier -> compute -> lgkmcnt(0)
// -> s_barrier [release buf for restage]. Never drains vmcnt mid-loop.
// LDS 64KB (K0|K1|V0|V1) -> 2 blocks/CU, grid 512 = exactly 2/CU.
// O-epilogue: two half-passes through a 17408-u16 OS overlay (doesn't fit 8 waves at once).
__global__ __launch_bounds__(512, 2) void attn_kernel(const u16* __restrict__ Q,
                                                      const u16* __restrict__ Kp,
                                                      const u16* __restrict__ Vtp,
                                                      u16* __restrict__ O) {
  __shared__ u16 lds[32768];          // 64KB: Kbuf0 | Kbuf1 | Vbuf0 | Vbuf1 (8192 u16 each)

  const int tid = threadIdx.x;
  const int lane = tid & 63;
  const int w = tid >> 6;             // 0..7
  const int l5 = lane & 31, hi = lane >> 5;
  const int bid = blockIdx.x;
  const int qt = 7 - (bid >> 6);      // 8 q-tiles of 256 rows; LPT (heavy first)
  const int hb = bid & 63;
  const int h = hb >> 2;
  const int b = hb & 3;
  const int kvh = h >> 2;
  const int q0 = qt * 256;
  const int wbase = tid - lane;
  const int wrow0 = q0 + w * 32;      // this wave's first q row
  const int qg = wrow0 + l5;          // this lane's q row

  const u16* Qb = Q + ((size_t)((b * 16 + h) * 2048 + wrow0)) * 128;
  const u16* Kb = Kp + (size_t)(b * 4 + kvh) * 2048 * 128;
  const u16* Vtb = Vtp + (size_t)(b * 4 + kvh) * 128 * 2048;

  bf16x8 qf[8];
#pragma unroll
  for (int ks = 0; ks < 8; ++ks)
    qf[ks] = *(const bf16x8*)(Qb + (size_t)l5 * 128 + ks * 16 + hi * 8);

  f32x16 oacc[4];
#pragma unroll
  for (int i = 0; i < 4; ++i) oacc[i] = (f32x16)0.0f;
  float m = -3.0e38f, l = 0.0f;

  const int nkt = 4 * qt + 4;

  auto stageKV = [&](int kt, int buf) {
    const int t0k = kt * 64;
    u16* Kd = lds + buf * 8192;
    u16* Vd = lds + 16384 + buf * 8192;
#pragma unroll
    for (int j = 0; j < 2; ++j) {
      int c = tid + j * 512;
      int row = c >> 4;
      int sboff = ((c & 15) * 16) ^ ((row & 15) << 4);
      gload_lds16(Kb + (size_t)(t0k + row) * 128 + (sboff >> 1),
                  Kd + (size_t)(wbase + j * 512) * 8);
    }
#pragma unroll
    for (int j = 0; j < 2; ++j) {
      int c = tid + j * 512;
      int d = c >> 3;
      int sboff = ((c & 7) * 16) ^ ((d & 7) << 4);
      gload_lds16(Vtb + (size_t)d * 2048 + t0k + (sboff >> 1),
                  Vd + (size_t)(wbase + j * 512) * 8);
    }
  };

  stageKV(0, 0);

  for (int kt = 0; kt < nkt; ++kt) {
    const int t0 = kt * 64;
    const int cur = kt & 1;
    if (kt + 1 < nkt) {
      stageKV(kt + 1, cur ^ 1);
      asm volatile("s_waitcnt vmcnt(4)" ::: "memory");
    } else {
      asm volatile("s_waitcnt vmcnt(0)" ::: "memory");
    }
    __builtin_amdgcn_s_barrier();      // buf[cur] staged by all waves

    if (t0 <= wrow0 + 31) {
      const char* ksb = (const char*)(lds + cur * 8192);
      const char* vtb = (const char*)(lds + 16384 + cur * 8192);

      // S^T = mfma(K, Q): p[kt2*16+r] = S[kv][q], kv = kt2*32 + (r&3)+8*(r>>2)+4*hi
      float p[32];
#pragma unroll
      for (int kt2 = 0; kt2 < 2; ++kt2) {
        f32x16 sacc = (f32x16)0.0f;
        int row = kt2 * 32 + l5;
#pragma unroll
        for (int ks = 0; ks < 8; ++ks) {
          bf16x8 kf = *(const bf16x8*)(ksb + row * 256 + ((ks * 32 + hi * 16) ^ ((row & 15) << 4)));
          sacc = __builtin_amdgcn_mfma_f32_32x32x16_bf16(kf, qf[ks], sacc, 0, 0, 0);
        }
#pragma unroll
        for (int r = 0; r < 16; ++r) p[kt2 * 16 + r] = sacc[r];
      }

      if (t0 + 63 > wrow0) {  // straddles diagonal: causal mask
#pragma unroll
        for (int kt2 = 0; kt2 < 2; ++kt2)
#pragma unroll
          for (int r = 0; r < 16; ++r) {
            int kvg = t0 + kt2 * 32 + (r & 3) + 8 * (r >> 2) + 4 * hi;
            if (kvg > qg) p[kt2 * 16 + r] = -3.0e38f;
          }
      }

      // in-lane row max + cross-half combine
      float mx[16];
#pragma unroll
      for (int i = 0; i < 16; ++i) mx[i] = fmaxf(p[i], p[i + 16]);
#pragma unroll
      for (int i = 0; i < 8; ++i) mx[i] = fmaxf(mx[i], mx[i + 8]);
#pragma unroll
      for (int i = 0; i < 4; ++i) mx[i] = fmaxf(mx[i], mx[i + 4]);
      float rm = fmaxf(fmaxf(mx[0], mx[1]), fmaxf(mx[2], mx[3]));
      rm = fmaxf(rm, __shfl_xor(rm, 32));

      bool defer = __all(rm <= m + 8.0f);
      if (!defer) {
        float mnew = fmaxf(m, rm);
        float sc = exp2f(m - mnew);
        m = mnew;
        l *= sc;
#pragma unroll
        for (int i = 0; i < 4; ++i)
#pragma unroll
          for (int r = 0; r < 16; ++r) oacc[i][r] *= sc;
      }

      // p = exp2(S - m); in-lane sum
#pragma unroll
      for (int i = 0; i < 32; ++i) p[i] = exp2f(p[i] - m);
      float sm[16];
#pragma unroll
      for (int i = 0; i < 16; ++i) sm[i] = p[i] + p[i + 16];
#pragma unroll
      for (int i = 0; i < 8; ++i) sm[i] += sm[i + 8];
#pragma unroll
      for (int i = 0; i < 4; ++i) sm[i] += sm[i + 4];
      float s2 = (sm[0] + sm[1]) + (sm[2] + sm[3]);
      s2 += __shfl_xor(s2, 32);
      l += s2;

      // P pack + redistribute + PV: O^T += mfma(A=V^T, B=P)
#pragma unroll
      for (int kt2 = 0; kt2 < 2; ++kt2) {
#pragma unroll
        for (int sl = 0; sl < 2; ++sl) {
          int base = kt2 * 16 + sl * 8;
          unsigned A0 = cvtpk(p[base + 0], p[base + 1]);
          unsigned A1 = cvtpk(p[base + 2], p[base + 3]);
          unsigned A2 = cvtpk(p[base + 4], p[base + 5]);
          unsigned A3 = cvtpk(p[base + 6], p[base + 7]);
          unsigned XA0 = __shfl_xor(A0, 32);
          unsigned XA1 = __shfl_xor(A1, 32);
          unsigned XA2 = __shfl_xor(A2, 32);
          unsigned XA3 = __shfl_xor(A3, 32);
          union { unsigned u[4]; bf16x8 v; } pf;
          pf.u[0] = hi ? XA2 : A0;
          pf.u[1] = hi ? XA3 : A1;
          pf.u[2] = hi ? A2 : XA0;
          pf.u[3] = hi ? A3 : XA1;
          int s = kt2 * 2 + sl;
#pragma unroll
          for (int dt = 0; dt < 4; ++dt) {
            int row = dt * 32 + l5;
            bf16x8 vb = *(const bf16x8*)(vtb + row * 128 + ((s * 32 + hi * 16) ^ ((row & 7) << 4)));
            oacc[dt] = __builtin_amdgcn_mfma_f32_32x32x16_bf16(vb, pf.v, oacc[dt], 0, 0, 0);
          }
        }
      }
    }

    asm volatile("s_waitcnt lgkmcnt(0)" ::: "memory");
    __builtin_amdgcn_s_barrier();      // all waves done reading buf[cur]
  }

  // normalize in-lane; two half-passes through OS overlay (waves 0-3, then 4-7)
  float inv = 1.0f / l;
  __syncthreads();
  for (int half = 0; half < 2; ++half) {
    if ((w >> 2) == half) {
      u16* OSw = lds + (w & 3) * 4352;     // [32 q][136] padded
#pragma unroll
      for (int dt = 0; dt < 4; ++dt)
#pragma unroll
        for (int r = 0; r < 16; ++r) {
          int d = dt * 32 + (r & 3) + 8 * (r >> 2) + 4 * hi;
          OSw[l5 * 136 + d] = f2bf(oacc[dt][r] * inv);
        }
    }
    __syncthreads();
    u16* Ob = O + ((size_t)(b * 2048 + q0 + half * 128)) * 2048 + h * 128;
#pragma unroll
    for (int j = 0; j < 4; ++j) {
      int c = tid + j * 512;
      int row = c >> 4, col = c & 15;
      *(bf16x8*)(Ob + (size_t)row * 2048 + col * 8) =
          *(const bf16x8*)&lds[(row >> 5) * 4352 + (row & 31) * 136 + col * 8];
    }
    __syncthreads();
  }
}

extern "C" void kernel_launch(void* const* d_in, const int* in_sizes, int n_in,
                              void* d_out, int out_size, void* d_ws, size_t ws_size,
                              hipStream_t stream) {
  (void)in_sizes; (void)n_in; (void)out_size; (void)ws_size;
  const float* x    = (const float*)d_in[0];
  const float* Wq   = (const float*)d_in[1];
  const float* Wk   = (const float*)d_in[2];
  const float* Wv   = (const float*)d_in[3];
  const float* Wo   = (const float*)d_in[4];
  const float* cosp = (const float*)d_in[5];
  const float* sinp = (const float*)d_in[6];

  u16* ws  = (u16*)d_ws;
  u16* xbf = ws;               // 16,777,216 elems (B*T x C)  -- reused as attn out
  u16* Wqb = xbf + 16777216;   //  4,194,304
  u16* Wkb = Wqb + 4194304;    //  1,048,576  } contiguous 1024x2048 KV weight
  u16* Wvb = Wkb + 1048576;    //  1,048,576  }
  u16* Wob = Wvb + 1048576;    //  4,194,304
  u16* Qb  = Wob + 4194304;    // 16,777,216 (B,H,T,D)
  u16* Kb  = Qb + 16777216;    //  4,194,304 (B,HKV,T,D)
  u16* Vb  = Kb + 4194304;     //  4,194,304 (B,HKV,D,T)  == V^T
  u16* AO  = xbf;              // attention output (B,T,C), reuses x region

  cast_all_kernel<<<2048, 256, 0, stream>>>(x, Wq, Wk, Wv, Wo, ws);

  const float qscale = (float)(1.4426950408889634 / sqrt(128.0));

  gemm_bt256<0><<<dim3(8, 32), 512, 0, stream>>>(xbf, Wqb, Qb, 8192, 2048, 2048, cosp, sinp, qscale);
  gemm_bt<3><<<dim3(8, 64), 256, 0, stream>>>(xbf, Wkb, Kb, Vb, 8192, 1024, 2048, cosp, sinp, 1.0f);

  attn_kernel<<<512, 512, 0, stream>>>(Qb, Kb, Vb, AO);

  gemm_bt256<2><<<dim3(8, 32), 512, 0, stream>>>(AO, Wob, d_out, 8192, 2048, 2048, nullptr, nullptr, 1.0f);
}